// Round 1
// baseline (6354.494 us; speedup 1.0000x reference)
//
#include <hip/hip_runtime.h>

// ---------------------------------------------------------------------------
// EdgeClassifierGNN: 2x GCNConv (128->64->64, sym-norm, self-loops) + edge MLP
// All fp32. Round 1: correctness-first structured baseline.
//   ws layout: deg/dinv [N], A [N*64], B [N*64]  (~26 MB)
// ---------------------------------------------------------------------------

__device__ __forceinline__ void fma4(float4& a, float s, const float4& b) {
    a.x = fmaf(s, b.x, a.x);
    a.y = fmaf(s, b.y, a.y);
    a.z = fmaf(s, b.z, a.z);
    a.w = fmaf(s, b.w, a.w);
}

__device__ __forceinline__ float4 relu4(float4 v) {
    v.x = fmaxf(v.x, 0.f); v.y = fmaxf(v.y, 0.f);
    v.z = fmaxf(v.z, 0.f); v.w = fmaxf(v.w, 0.f);
    return v;
}

// deg[d] += 1 per edge (self-loop +1 folded into k_dinv)
__global__ void k_deg(const int* __restrict__ dst, float* __restrict__ deg, int E) {
    int e = blockIdx.x * 256 + threadIdx.x;
    if (e < E) atomicAdd(&deg[dst[e]], 1.0f);
}

// in-place: deg -> rsqrt(deg + 1)   (deg>=1 after self-loop, so no max needed)
__global__ void k_dinv(float* __restrict__ deg, int N) {
    int i = blockIdx.x * 256 + threadIdx.x;
    if (i < N) deg[i] = rsqrtf(deg[i] + 1.0f);
}

// C[M x 64] = op(A[M x K]) @ B[K x 64]; op = relu if RELU_A.
// A staged row-major in LDS with row stride K+4 (odd*4 -> <=2-way bank alias).
// B staged in 64-row chunks to keep static LDS < 64 KB.
template<int K, bool RELU_A>
__global__ __launch_bounds__(256) void k_gemm(const float* __restrict__ A,
                                              const float* __restrict__ B,
                                              float* __restrict__ C, int M) {
    constexpr int AS = K + 4;
    __shared__ float As[64 * AS];
    __shared__ float Bs[64 * 64];
    const int t = threadIdx.x;
    const int r0 = blockIdx.x * 64;

    constexpr int C4 = K / 4;  // float4s per A row
    for (int idx = t; idx < 64 * C4; idx += 256) {
        int row = idx / C4, c4 = idx % C4;
        float4 v = make_float4(0.f, 0.f, 0.f, 0.f);
        if (r0 + row < M)
            v = reinterpret_cast<const float4*>(A + (size_t)(r0 + row) * K)[c4];
        if (RELU_A) v = relu4(v);
        *reinterpret_cast<float4*>(&As[row * AS + 4 * c4]) = v;
    }

    const int tx = t & 15, ty = t >> 4;  // 16 cols-of-4 x 16 rows-of-4
    float4 acc[4];
    acc[0] = acc[1] = acc[2] = acc[3] = make_float4(0.f, 0.f, 0.f, 0.f);

    for (int c = 0; c < K / 64; c++) {
        __syncthreads();  // protects As (c==0) and Bs reuse (c>0)
        for (int idx = t; idx < 64 * 16; idx += 256)
            reinterpret_cast<float4*>(Bs)[idx] =
                reinterpret_cast<const float4*>(B + (size_t)c * 64 * 64)[idx];
        __syncthreads();
#pragma unroll
        for (int k0 = 0; k0 < 64; k0 += 4) {
            float4 b0 = *reinterpret_cast<const float4*>(&Bs[(k0 + 0) * 64 + 4 * tx]);
            float4 b1 = *reinterpret_cast<const float4*>(&Bs[(k0 + 1) * 64 + 4 * tx]);
            float4 b2 = *reinterpret_cast<const float4*>(&Bs[(k0 + 2) * 64 + 4 * tx]);
            float4 b3 = *reinterpret_cast<const float4*>(&Bs[(k0 + 3) * 64 + 4 * tx]);
#pragma unroll
            for (int i = 0; i < 4; i++) {
                float4 a = *reinterpret_cast<const float4*>(
                    &As[(4 * ty + i) * AS + c * 64 + k0]);
                fma4(acc[i], a.x, b0);
                fma4(acc[i], a.y, b1);
                fma4(acc[i], a.z, b2);
                fma4(acc[i], a.w, b3);
            }
        }
    }

#pragma unroll
    for (int i = 0; i < 4; i++) {
        int row = r0 + 4 * ty + i;
        if (row < M)
            *reinterpret_cast<float4*>(C + (size_t)row * 64 + 4 * tx) = acc[i];
    }
}

// out[i] = bias + dinv[i]^2 * hlin[i]   (self-loop message + bias)
__global__ void k_init(const float* __restrict__ hlin, const float* __restrict__ dinv,
                       const float* __restrict__ bias, float* __restrict__ out, int N) {
    int tid = blockIdx.x * 256 + threadIdx.x;
    int i = tid >> 4, q = tid & 15;
    if (i >= N) return;
    float di = dinv[i];
    float w = di * di;
    float4 h = reinterpret_cast<const float4*>(hlin + (size_t)i * 64)[q];
    float4 b = reinterpret_cast<const float4*>(bias)[q];
    float4 o = make_float4(fmaf(w, h.x, b.x), fmaf(w, h.y, b.y),
                           fmaf(w, h.z, b.z), fmaf(w, h.w, b.w));
    reinterpret_cast<float4*>(out + (size_t)i * 64)[q] = o;
}

// out[dst] += dinv[src]*dinv[dst] * hlin[src]; 4 threads/edge, 16 floats each
__global__ void k_scatter(const float* __restrict__ hlin, const int* __restrict__ src,
                          const int* __restrict__ dst, const float* __restrict__ dinv,
                          float* __restrict__ out, int E) {
    int tid = blockIdx.x * 256 + threadIdx.x;
    int e = tid >> 2, q = tid & 3;
    if (e >= E) return;
    int s = src[e], d = dst[e];
    float norm = dinv[s] * dinv[d];
    const float* hp = hlin + (size_t)s * 64 + q * 16;
    float* op = out + (size_t)d * 64 + q * 16;
#pragma unroll
    for (int j = 0; j < 4; j++) {
        float4 v = reinterpret_cast<const float4*>(hp)[j];
        atomicAdd(op + 4 * j + 0, norm * v.x);
        atomicAdd(op + 4 * j + 1, norm * v.y);
        atomicAdd(op + 4 * j + 2, norm * v.z);
        atomicAdd(op + 4 * j + 3, norm * v.w);
    }
}

// Fused edge MLP: out = relu([relu(h2[s]) | relu(h2[d]) | ea] @ Wm1 + bm1) @ Wm2 + bm2
// 64 edges/block. A tile 64x144 (stride 148) in LDS; Wm1 staged in two 72-row
// halves (total static LDS 56.3 KB < 64 KB). 4x4 micro-tile then shfl-reduce.
__global__ __launch_bounds__(256) void k_edgemlp(
    const float* __restrict__ h2, const int* __restrict__ src,
    const int* __restrict__ dst, const float* __restrict__ ea,
    const float* __restrict__ Wm1, const float* __restrict__ bm1,
    const float* __restrict__ Wm2, const float* __restrict__ bm2,
    float* __restrict__ out, int E) {
    constexpr int AS = 148;
    __shared__ float Ae[64 * AS];  // 37888 B
    __shared__ float Bs[72 * 64];  // 18432 B
    const int t = threadIdx.x;
    const int e0 = blockIdx.x * 64;

    {
        int j = t & 15;   // feature float4 within the 64-float half
        int el = t >> 4;  // edge slot 0..15, 4 passes
#pragma unroll
        for (int p = 0; p < 4; p++) {
            int eli = el + 16 * p;
            int e = e0 + eli;
            int s = src[e], d = dst[e];
            float4 v = relu4(reinterpret_cast<const float4*>(h2 + (size_t)s * 64)[j]);
            *reinterpret_cast<float4*>(&Ae[eli * AS + 4 * j]) = v;
            float4 w = relu4(reinterpret_cast<const float4*>(h2 + (size_t)d * 64)[j]);
            *reinterpret_cast<float4*>(&Ae[eli * AS + 64 + 4 * j]) = w;
        }
        int el2 = t >> 2, j2 = t & 3;  // edge_attr: 16 floats/edge
        float4 u = reinterpret_cast<const float4*>(ea + (size_t)(e0 + el2) * 16)[j2];
        *reinterpret_cast<float4*>(&Ae[el2 * AS + 128 + 4 * j2]) = u;
    }

    const int tx = t & 15, ty = t >> 4;
    float4 acc[4];
    acc[0] = acc[1] = acc[2] = acc[3] = make_float4(0.f, 0.f, 0.f, 0.f);

    for (int half = 0; half < 2; half++) {
        __syncthreads();
        for (int idx = t; idx < 72 * 16; idx += 256)
            reinterpret_cast<float4*>(Bs)[idx] =
                reinterpret_cast<const float4*>(Wm1 + half * 72 * 64)[idx];
        __syncthreads();
#pragma unroll
        for (int k0 = 0; k0 < 72; k0 += 4) {
            float4 b0 = *reinterpret_cast<const float4*>(&Bs[(k0 + 0) * 64 + 4 * tx]);
            float4 b1 = *reinterpret_cast<const float4*>(&Bs[(k0 + 1) * 64 + 4 * tx]);
            float4 b2 = *reinterpret_cast<const float4*>(&Bs[(k0 + 2) * 64 + 4 * tx]);
            float4 b3 = *reinterpret_cast<const float4*>(&Bs[(k0 + 3) * 64 + 4 * tx]);
#pragma unroll
            for (int i = 0; i < 4; i++) {
                float4 a = *reinterpret_cast<const float4*>(
                    &Ae[(4 * ty + i) * AS + half * 72 + k0]);
                fma4(acc[i], a.x, b0);
                fma4(acc[i], a.y, b1);
                fma4(acc[i], a.z, b2);
                fma4(acc[i], a.w, b3);
            }
        }
    }

    // second layer: +bm1, relu, x Wm2[64x2]; partial over this thread's 4 cols
    float w20[4], w21[4], bb[4];
#pragma unroll
    for (int j = 0; j < 4; j++) {
        int c = 4 * tx + j;
        bb[j] = bm1[c];
        w20[j] = Wm2[2 * c];
        w21[j] = Wm2[2 * c + 1];
    }
    float p0[4], p1[4];
#pragma unroll
    for (int i = 0; i < 4; i++) {
        float h0 = fmaxf(acc[i].x + bb[0], 0.f);
        float h1 = fmaxf(acc[i].y + bb[1], 0.f);
        float h2v = fmaxf(acc[i].z + bb[2], 0.f);
        float h3 = fmaxf(acc[i].w + bb[3], 0.f);
        p0[i] = h0 * w20[0] + h1 * w20[1] + h2v * w20[2] + h3 * w20[3];
        p1[i] = h0 * w21[0] + h1 * w21[1] + h2v * w21[2] + h3 * w21[3];
    }
    // reduce across the 16 tx lanes (lane bits 0..3 within the wave)
#pragma unroll
    for (int sft = 1; sft < 16; sft <<= 1) {
#pragma unroll
        for (int i = 0; i < 4; i++) {
            p0[i] += __shfl_xor(p0[i], sft);
            p1[i] += __shfl_xor(p1[i], sft);
        }
    }
    if (tx == 0) {
        float c0 = bm2[0], c1 = bm2[1];
        float4 o0 = make_float4(p0[0] + c0, p1[0] + c1, p0[1] + c0, p1[1] + c1);
        float4 o1 = make_float4(p0[2] + c0, p1[2] + c1, p0[3] + c0, p1[3] + c1);
        float* dest = out + (size_t)(e0 + 4 * ty) * 2;
        reinterpret_cast<float4*>(dest)[0] = o0;
        reinterpret_cast<float4*>(dest)[1] = o1;
    }
}

extern "C" void kernel_launch(void* const* d_in, const int* in_sizes, int n_in,
                              void* d_out, int out_size, void* d_ws, size_t ws_size,
                              hipStream_t stream) {
    const float* x = (const float*)d_in[0];
    const int* ei = (const int*)d_in[1];
    const float* ea = (const float*)d_in[2];
    const float* W1 = (const float*)d_in[3];
    const float* b1 = (const float*)d_in[4];
    const float* W2 = (const float*)d_in[5];
    const float* b2 = (const float*)d_in[6];
    const float* Wm1 = (const float*)d_in[7];
    const float* bm1 = (const float*)d_in[8];
    const float* Wm2 = (const float*)d_in[9];
    const float* bm2 = (const float*)d_in[10];

    const int N = in_sizes[0] / 128;  // 50000
    const int E = in_sizes[1] / 2;    // 800000
    const int* src = ei;
    const int* dst = ei + E;
    float* out = (float*)d_out;

    float* ws = (float*)d_ws;
    size_t algn = (((size_t)N + 255) / 256) * 256;
    float* deg = ws;                   // N (becomes dinv in place)
    float* A = ws + algn;              // N*64: h_lin ping
    float* B = A + (size_t)N * 64;     // N*64: h_agg pong

    hipMemsetAsync(deg, 0, (size_t)N * sizeof(float), stream);
    k_deg<<<(E + 255) / 256, 256, 0, stream>>>(dst, deg, E);
    k_dinv<<<(N + 255) / 256, 256, 0, stream>>>(deg, N);

    // Layer 1: A = x @ W1; B = b1 + dinv^2*A; B += scatter(norm * A[src])
    k_gemm<128, false><<<(N + 63) / 64, 256, 0, stream>>>(x, W1, A, N);
    k_init<<<(N * 16 + 255) / 256, 256, 0, stream>>>(A, deg, b1, B, N);
    k_scatter<<<(E * 4 + 255) / 256, 256, 0, stream>>>(A, src, dst, deg, B, E);

    // Layer 2: A = relu(B) @ W2; B = b2 + dinv^2*A; B += scatter(norm * A[src])
    k_gemm<64, true><<<(N + 63) / 64, 256, 0, stream>>>(B, W2, A, N);
    k_init<<<(N * 16 + 255) / 256, 256, 0, stream>>>(A, deg, b2, B, N);
    k_scatter<<<(E * 4 + 255) / 256, 256, 0, stream>>>(A, src, dst, deg, B, E);

    // Edge MLP (relu of h2 folded into gather)
    k_edgemlp<<<E / 64, 256, 0, stream>>>(B, src, dst, ea, Wm1, bm1, Wm2, bm2,
                                          out, E);
}

// Round 2
// 619.747 us; speedup vs baseline: 10.2534x; 10.2534x over previous
//
#include <hip/hip_runtime.h>

// ---------------------------------------------------------------------------
// EdgeClassifierGNN: 2x GCNConv (128->64->64, sym-norm, self-loops) + edge MLP
// Round 2: replace fp32 scatter-atomics (2x 2.94 ms, 1.6 GB WRITE_SIZE each)
// with counting-sort CSR + gather-style aggregation (no fp32 atomics).
//   dinv[src] scaling folded into GEMM epilogue: A = dinv[row] * (X @ W)[row]
//   agg: out[d] = bias + dinv[d] * (A[d] + sum_{s in N(d)} A[s])
// ---------------------------------------------------------------------------

__device__ __forceinline__ void fma4(float4& a, float s, const float4& b) {
    a.x = fmaf(s, b.x, a.x);
    a.y = fmaf(s, b.y, a.y);
    a.z = fmaf(s, b.z, a.z);
    a.w = fmaf(s, b.w, a.w);
}

__device__ __forceinline__ float4 relu4(float4 v) {
    v.x = fmaxf(v.x, 0.f); v.y = fmaxf(v.y, 0.f);
    v.z = fmaxf(v.z, 0.f); v.w = fmaxf(v.w, 0.f);
    return v;
}

// cnt[d] += 1 per edge (int atomics; self-loop folded into k_dinv)
__global__ void k_count(const int* __restrict__ dst, int* __restrict__ cnt, int E) {
    int e = blockIdx.x * 256 + threadIdx.x;
    if (e < E) atomicAdd(&cnt[dst[e]], 1);
}

// dinv[i] = rsqrt(cnt[i] + 1)
__global__ void k_dinv(const int* __restrict__ cnt, float* __restrict__ dinv, int N) {
    int i = blockIdx.x * 256 + threadIdx.x;
    if (i < N) dinv[i] = rsqrtf((float)cnt[i] + 1.0f);
}

// Exclusive prefix sum of cnt[0..N) -> row_ptr[0..N], single block of 1024.
__global__ __launch_bounds__(1024) void k_scan(const int* __restrict__ cnt,
                                               int* __restrict__ row_ptr, int N) {
    __shared__ int wsum[16];
    __shared__ int s_carry;
    const int t = threadIdx.x;
    const int lane = t & 63;
    const int w = t >> 6;
    if (t == 0) s_carry = 0;
    __syncthreads();
    for (int base = 0; base < N; base += 1024) {
        int i = base + t;
        int v = (i < N) ? cnt[i] : 0;
        int x = v;  // inclusive wave scan
#pragma unroll
        for (int d = 1; d < 64; d <<= 1) {
            int y = __shfl_up(x, d);
            if (lane >= d) x += y;
        }
        if (lane == 63) wsum[w] = x;
        __syncthreads();
        if (w == 0 && lane < 16) {  // inclusive scan of 16 wave sums
            int y = wsum[lane];
#pragma unroll
            for (int d = 1; d < 16; d <<= 1) {
                int z = __shfl_up(y, d);
                if (lane >= d) y += z;
            }
            wsum[lane] = y;
        }
        __syncthreads();
        int woff = (w == 0) ? 0 : wsum[w - 1];
        if (i < N) row_ptr[i] = s_carry + woff + x - v;  // exclusive
        __syncthreads();
        if (t == 0) s_carry += wsum[15];
        __syncthreads();
    }
    if (threadIdx.x == 0) row_ptr[N] = s_carry;
}

// csr_src[row_ptr[d] + cur[d]++] = src  (cur pre-zeroed)
__global__ void k_fill(const int* __restrict__ src, const int* __restrict__ dst,
                       const int* __restrict__ row_ptr, int* __restrict__ cur,
                       int* __restrict__ csr_src, int E) {
    int e = blockIdx.x * 256 + threadIdx.x;
    if (e >= E) return;
    int d = dst[e];
    int pos = atomicAdd(&cur[d], 1);
    csr_src[row_ptr[d] + pos] = src[e];
}

// C[M x 64] = dinv[row] * (op(A[M x K]) @ B[K x 64]); op = relu if RELU_A.
template<int K, bool RELU_A>
__global__ __launch_bounds__(256) void k_gemm(const float* __restrict__ A,
                                              const float* __restrict__ B,
                                              const float* __restrict__ dinv,
                                              float* __restrict__ C, int M) {
    constexpr int AS = K + 4;
    __shared__ float As[64 * AS];
    __shared__ float Bs[64 * 64];
    const int t = threadIdx.x;
    const int r0 = blockIdx.x * 64;

    constexpr int C4 = K / 4;  // float4s per A row
    for (int idx = t; idx < 64 * C4; idx += 256) {
        int row = idx / C4, c4 = idx % C4;
        float4 v = make_float4(0.f, 0.f, 0.f, 0.f);
        if (r0 + row < M)
            v = reinterpret_cast<const float4*>(A + (size_t)(r0 + row) * K)[c4];
        if (RELU_A) v = relu4(v);
        *reinterpret_cast<float4*>(&As[row * AS + 4 * c4]) = v;
    }

    const int tx = t & 15, ty = t >> 4;  // 16 cols-of-4 x 16 rows-of-4
    float4 acc[4];
    acc[0] = acc[1] = acc[2] = acc[3] = make_float4(0.f, 0.f, 0.f, 0.f);

    for (int c = 0; c < K / 64; c++) {
        __syncthreads();
        for (int idx = t; idx < 64 * 16; idx += 256)
            reinterpret_cast<float4*>(Bs)[idx] =
                reinterpret_cast<const float4*>(B + (size_t)c * 64 * 64)[idx];
        __syncthreads();
#pragma unroll
        for (int k0 = 0; k0 < 64; k0 += 4) {
            float4 b0 = *reinterpret_cast<const float4*>(&Bs[(k0 + 0) * 64 + 4 * tx]);
            float4 b1 = *reinterpret_cast<const float4*>(&Bs[(k0 + 1) * 64 + 4 * tx]);
            float4 b2 = *reinterpret_cast<const float4*>(&Bs[(k0 + 2) * 64 + 4 * tx]);
            float4 b3 = *reinterpret_cast<const float4*>(&Bs[(k0 + 3) * 64 + 4 * tx]);
#pragma unroll
            for (int i = 0; i < 4; i++) {
                float4 a = *reinterpret_cast<const float4*>(
                    &As[(4 * ty + i) * AS + c * 64 + k0]);
                fma4(acc[i], a.x, b0);
                fma4(acc[i], a.y, b1);
                fma4(acc[i], a.z, b2);
                fma4(acc[i], a.w, b3);
            }
        }
    }

#pragma unroll
    for (int i = 0; i < 4; i++) {
        int row = r0 + 4 * ty + i;
        if (row < M) {
            float di = dinv[row];
            float4 o = make_float4(di * acc[i].x, di * acc[i].y,
                                   di * acc[i].z, di * acc[i].w);
            *reinterpret_cast<float4*>(C + (size_t)row * 64 + 4 * tx) = o;
        }
    }
}

// One wave per node: out[d] = bias + dinv[d] * (As[d] + sum_s As[s])
// As is pre-scaled by dinv[src]. Each edge = one coalesced 256B wave load.
__global__ __launch_bounds__(256) void k_agg(const float* __restrict__ As,
                                             const int* __restrict__ row_ptr,
                                             const int* __restrict__ csr_src,
                                             const float* __restrict__ dinv,
                                             const float* __restrict__ bias,
                                             float* __restrict__ out, int N) {
    int node = blockIdx.x * 4 + (threadIdx.x >> 6);
    int lane = threadIdx.x & 63;
    if (node >= N) return;
    int beg = row_ptr[node], end = row_ptr[node + 1];
    float acc = As[(size_t)node * 64 + lane];  // self loop (already dinv-scaled)
    for (int p = beg; p < end; p += 64) {
        int m = min(64, end - p);
        int sl = (p + lane < end) ? csr_src[p + lane] : 0;
        int j = 0;
        for (; j + 1 < m; j += 2) {  // 2 independent loads in flight
            int s0 = __shfl(sl, j);
            int s1 = __shfl(sl, j + 1);
            float v0 = As[(size_t)s0 * 64 + lane];
            float v1 = As[(size_t)s1 * 64 + lane];
            acc += v0;
            acc += v1;
        }
        if (j < m) {
            int s0 = __shfl(sl, j);
            acc += As[(size_t)s0 * 64 + lane];
        }
    }
    out[(size_t)node * 64 + lane] = fmaf(dinv[node], acc, bias[lane]);
}

// Fused edge MLP: out = relu([relu(h2[s]) | relu(h2[d]) | ea] @ Wm1 + bm1) @ Wm2 + bm2
__global__ __launch_bounds__(256) void k_edgemlp(
    const float* __restrict__ h2, const int* __restrict__ src,
    const int* __restrict__ dst, const float* __restrict__ ea,
    const float* __restrict__ Wm1, const float* __restrict__ bm1,
    const float* __restrict__ Wm2, const float* __restrict__ bm2,
    float* __restrict__ out, int E) {
    constexpr int AS = 148;
    __shared__ float Ae[64 * AS];  // 37888 B
    __shared__ float Bs[72 * 64];  // 18432 B
    const int t = threadIdx.x;
    const int e0 = blockIdx.x * 64;

    {
        int j = t & 15;   // feature float4 within the 64-float half
        int el = t >> 4;  // edge slot 0..15, 4 passes
#pragma unroll
        for (int p = 0; p < 4; p++) {
            int eli = el + 16 * p;
            int e = e0 + eli;
            int s = src[e], d = dst[e];
            float4 v = relu4(reinterpret_cast<const float4*>(h2 + (size_t)s * 64)[j]);
            *reinterpret_cast<float4*>(&Ae[eli * AS + 4 * j]) = v;
            float4 w = relu4(reinterpret_cast<const float4*>(h2 + (size_t)d * 64)[j]);
            *reinterpret_cast<float4*>(&Ae[eli * AS + 64 + 4 * j]) = w;
        }
        int el2 = t >> 2, j2 = t & 3;  // edge_attr: 16 floats/edge
        float4 u = reinterpret_cast<const float4*>(ea + (size_t)(e0 + el2) * 16)[j2];
        *reinterpret_cast<float4*>(&Ae[el2 * AS + 128 + 4 * j2]) = u;
    }

    const int tx = t & 15, ty = t >> 4;
    float4 acc[4];
    acc[0] = acc[1] = acc[2] = acc[3] = make_float4(0.f, 0.f, 0.f, 0.f);

    for (int half = 0; half < 2; half++) {
        __syncthreads();
        for (int idx = t; idx < 72 * 16; idx += 256)
            reinterpret_cast<float4*>(Bs)[idx] =
                reinterpret_cast<const float4*>(Wm1 + half * 72 * 64)[idx];
        __syncthreads();
#pragma unroll
        for (int k0 = 0; k0 < 72; k0 += 4) {
            float4 b0 = *reinterpret_cast<const float4*>(&Bs[(k0 + 0) * 64 + 4 * tx]);
            float4 b1 = *reinterpret_cast<const float4*>(&Bs[(k0 + 1) * 64 + 4 * tx]);
            float4 b2 = *reinterpret_cast<const float4*>(&Bs[(k0 + 2) * 64 + 4 * tx]);
            float4 b3 = *reinterpret_cast<const float4*>(&Bs[(k0 + 3) * 64 + 4 * tx]);
#pragma unroll
            for (int i = 0; i < 4; i++) {
                float4 a = *reinterpret_cast<const float4*>(
                    &Ae[(4 * ty + i) * AS + half * 72 + k0]);
                fma4(acc[i], a.x, b0);
                fma4(acc[i], a.y, b1);
                fma4(acc[i], a.z, b2);
                fma4(acc[i], a.w, b3);
            }
        }
    }

    float w20[4], w21[4], bb[4];
#pragma unroll
    for (int j = 0; j < 4; j++) {
        int c = 4 * tx + j;
        bb[j] = bm1[c];
        w20[j] = Wm2[2 * c];
        w21[j] = Wm2[2 * c + 1];
    }
    float p0[4], p1[4];
#pragma unroll
    for (int i = 0; i < 4; i++) {
        float h0 = fmaxf(acc[i].x + bb[0], 0.f);
        float h1 = fmaxf(acc[i].y + bb[1], 0.f);
        float h2v = fmaxf(acc[i].z + bb[2], 0.f);
        float h3 = fmaxf(acc[i].w + bb[3], 0.f);
        p0[i] = h0 * w20[0] + h1 * w20[1] + h2v * w20[2] + h3 * w20[3];
        p1[i] = h0 * w21[0] + h1 * w21[1] + h2v * w21[2] + h3 * w21[3];
    }
#pragma unroll
    for (int sft = 1; sft < 16; sft <<= 1) {
#pragma unroll
        for (int i = 0; i < 4; i++) {
            p0[i] += __shfl_xor(p0[i], sft);
            p1[i] += __shfl_xor(p1[i], sft);
        }
    }
    if (tx == 0) {
        float c0 = bm2[0], c1 = bm2[1];
        float4 o0 = make_float4(p0[0] + c0, p1[0] + c1, p0[1] + c0, p1[1] + c1);
        float4 o1 = make_float4(p0[2] + c0, p1[2] + c1, p0[3] + c0, p1[3] + c1);
        float* dest = out + (size_t)(e0 + 4 * ty) * 2;
        reinterpret_cast<float4*>(dest)[0] = o0;
        reinterpret_cast<float4*>(dest)[1] = o1;
    }
}

static inline size_t align256(size_t x) { return (x + 255) & ~(size_t)255; }

extern "C" void kernel_launch(void* const* d_in, const int* in_sizes, int n_in,
                              void* d_out, int out_size, void* d_ws, size_t ws_size,
                              hipStream_t stream) {
    const float* x = (const float*)d_in[0];
    const int* ei = (const int*)d_in[1];
    const float* ea = (const float*)d_in[2];
    const float* W1 = (const float*)d_in[3];
    const float* b1 = (const float*)d_in[4];
    const float* W2 = (const float*)d_in[5];
    const float* b2 = (const float*)d_in[6];
    const float* Wm1 = (const float*)d_in[7];
    const float* bm1 = (const float*)d_in[8];
    const float* Wm2 = (const float*)d_in[9];
    const float* bm2 = (const float*)d_in[10];

    const int N = in_sizes[0] / 128;  // 50000
    const int E = in_sizes[1] / 2;    // 800000
    const int* src = ei;
    const int* dst = ei + E;
    float* out = (float*)d_out;

    // ws layout (256B-aligned chunks)
    char* p = (char*)d_ws;
    int* cnt = (int*)p;        p += align256((size_t)N * 4);
    int* cur = (int*)p;        p += align256((size_t)N * 4);
    int* row_ptr = (int*)p;    p += align256((size_t)(N + 1) * 4);
    int* csr_src = (int*)p;    p += align256((size_t)E * 4);
    float* dinv = (float*)p;   p += align256((size_t)N * 4);
    float* A = (float*)p;      p += align256((size_t)N * 64 * 4);
    float* B = (float*)p;

    // ---- CSR build (counting sort by dst) ----
    hipMemsetAsync(cnt, 0, (size_t)N * sizeof(int), stream);
    hipMemsetAsync(cur, 0, (size_t)N * sizeof(int), stream);
    k_count<<<(E + 255) / 256, 256, 0, stream>>>(dst, cnt, E);
    k_dinv<<<(N + 255) / 256, 256, 0, stream>>>(cnt, dinv, N);
    k_scan<<<1, 1024, 0, stream>>>(cnt, row_ptr, N);
    k_fill<<<(E + 255) / 256, 256, 0, stream>>>(src, dst, row_ptr, cur, csr_src, E);

    // ---- Layer 1: A = dinv*(x@W1); B = b1 + dinv[d]*(A[d] + sum A[s]) ----
    k_gemm<128, false><<<(N + 63) / 64, 256, 0, stream>>>(x, W1, dinv, A, N);
    k_agg<<<(N + 3) / 4, 256, 0, stream>>>(A, row_ptr, csr_src, dinv, b1, B, N);

    // ---- Layer 2 ----
    k_gemm<64, true><<<(N + 63) / 64, 256, 0, stream>>>(B, W2, dinv, A, N);
    k_agg<<<(N + 3) / 4, 256, 0, stream>>>(A, row_ptr, csr_src, dinv, b2, B, N);

    // ---- Edge MLP ----
    k_edgemlp<<<E / 64, 256, 0, stream>>>(B, src, dst, ea, Wm1, bm1, Wm2, bm2,
                                          out, E);
}

// Round 3
// 489.482 us; speedup vs baseline: 12.9821x; 1.2661x over previous
//
#include <hip/hip_runtime.h>

// ---------------------------------------------------------------------------
// EdgeClassifierGNN: 2x GCNConv (128->64->64, sym-norm, self-loops) + edge MLP
// Round 3: decompose edge MLP:  [h_s|h_d|ea]@Wm1 = h_s@W_s + h_d@W_d + ea@W_e
//   -> per-NODE projections Ps,Pd (50K rows, tiled GEMM) + cheap per-edge
//      kernel (gather + inline 16x64 ea-proj + relu + 64->2 dot, no LDS).
// ---------------------------------------------------------------------------

__device__ __forceinline__ void fma4(float4& a, float s, const float4& b) {
    a.x = fmaf(s, b.x, a.x);
    a.y = fmaf(s, b.y, a.y);
    a.z = fmaf(s, b.z, a.z);
    a.w = fmaf(s, b.w, a.w);
}

__device__ __forceinline__ float4 relu4(float4 v) {
    v.x = fmaxf(v.x, 0.f); v.y = fmaxf(v.y, 0.f);
    v.z = fmaxf(v.z, 0.f); v.w = fmaxf(v.w, 0.f);
    return v;
}

// cnt[d] += 1 per edge (int atomics; self-loop folded into k_dinv)
__global__ void k_count(const int* __restrict__ dst, int* __restrict__ cnt, int E) {
    int e = blockIdx.x * 256 + threadIdx.x;
    if (e < E) atomicAdd(&cnt[dst[e]], 1);
}

// dinv[i] = rsqrt(cnt[i] + 1)
__global__ void k_dinv(const int* __restrict__ cnt, float* __restrict__ dinv, int N) {
    int i = blockIdx.x * 256 + threadIdx.x;
    if (i < N) dinv[i] = rsqrtf((float)cnt[i] + 1.0f);
}

// Exclusive prefix sum of cnt[0..N) -> row_ptr[0..N], single block of 1024.
__global__ __launch_bounds__(1024) void k_scan(const int* __restrict__ cnt,
                                               int* __restrict__ row_ptr, int N) {
    __shared__ int wsum[16];
    __shared__ int s_carry;
    const int t = threadIdx.x;
    const int lane = t & 63;
    const int w = t >> 6;
    if (t == 0) s_carry = 0;
    __syncthreads();
    for (int base = 0; base < N; base += 1024) {
        int i = base + t;
        int v = (i < N) ? cnt[i] : 0;
        int x = v;  // inclusive wave scan
#pragma unroll
        for (int d = 1; d < 64; d <<= 1) {
            int y = __shfl_up(x, d);
            if (lane >= d) x += y;
        }
        if (lane == 63) wsum[w] = x;
        __syncthreads();
        if (w == 0 && lane < 16) {  // inclusive scan of 16 wave sums
            int y = wsum[lane];
#pragma unroll
            for (int d = 1; d < 16; d <<= 1) {
                int z = __shfl_up(y, d);
                if (lane >= d) y += z;
            }
            wsum[lane] = y;
        }
        __syncthreads();
        int woff = (w == 0) ? 0 : wsum[w - 1];
        if (i < N) row_ptr[i] = s_carry + woff + x - v;  // exclusive
        __syncthreads();
        if (t == 0) s_carry += wsum[15];
        __syncthreads();
    }
    if (threadIdx.x == 0) row_ptr[N] = s_carry;
}

// csr_src[row_ptr[d] + cur[d]++] = src  (cur pre-zeroed)
__global__ void k_fill(const int* __restrict__ src, const int* __restrict__ dst,
                       const int* __restrict__ row_ptr, int* __restrict__ cur,
                       int* __restrict__ csr_src, int E) {
    int e = blockIdx.x * 256 + threadIdx.x;
    if (e >= E) return;
    int d = dst[e];
    int pos = atomicAdd(&cur[d], 1);
    csr_src[row_ptr[d] + pos] = src[e];
}

// C[M x 64] = scale? dinv[row]* : 1 * (op(A[M x K]) @ B[K x 64]); op=relu if RELU_A
template<int K, bool RELU_A, bool SCALE>
__global__ __launch_bounds__(256) void k_gemm(const float* __restrict__ A,
                                              const float* __restrict__ B,
                                              const float* __restrict__ dinv,
                                              float* __restrict__ C, int M) {
    constexpr int AS = K + 4;
    __shared__ float As[64 * AS];
    __shared__ float Bs[64 * 64];
    const int t = threadIdx.x;
    const int r0 = blockIdx.x * 64;

    constexpr int C4 = K / 4;  // float4s per A row
    for (int idx = t; idx < 64 * C4; idx += 256) {
        int row = idx / C4, c4 = idx % C4;
        float4 v = make_float4(0.f, 0.f, 0.f, 0.f);
        if (r0 + row < M)
            v = reinterpret_cast<const float4*>(A + (size_t)(r0 + row) * K)[c4];
        if (RELU_A) v = relu4(v);
        *reinterpret_cast<float4*>(&As[row * AS + 4 * c4]) = v;
    }

    const int tx = t & 15, ty = t >> 4;  // 16 cols-of-4 x 16 rows-of-4
    float4 acc[4];
    acc[0] = acc[1] = acc[2] = acc[3] = make_float4(0.f, 0.f, 0.f, 0.f);

    for (int c = 0; c < K / 64; c++) {
        __syncthreads();
        for (int idx = t; idx < 64 * 16; idx += 256)
            reinterpret_cast<float4*>(Bs)[idx] =
                reinterpret_cast<const float4*>(B + (size_t)c * 64 * 64)[idx];
        __syncthreads();
#pragma unroll
        for (int k0 = 0; k0 < 64; k0 += 4) {
            float4 b0 = *reinterpret_cast<const float4*>(&Bs[(k0 + 0) * 64 + 4 * tx]);
            float4 b1 = *reinterpret_cast<const float4*>(&Bs[(k0 + 1) * 64 + 4 * tx]);
            float4 b2 = *reinterpret_cast<const float4*>(&Bs[(k0 + 2) * 64 + 4 * tx]);
            float4 b3 = *reinterpret_cast<const float4*>(&Bs[(k0 + 3) * 64 + 4 * tx]);
#pragma unroll
            for (int i = 0; i < 4; i++) {
                float4 a = *reinterpret_cast<const float4*>(
                    &As[(4 * ty + i) * AS + c * 64 + k0]);
                fma4(acc[i], a.x, b0);
                fma4(acc[i], a.y, b1);
                fma4(acc[i], a.z, b2);
                fma4(acc[i], a.w, b3);
            }
        }
    }

#pragma unroll
    for (int i = 0; i < 4; i++) {
        int row = r0 + 4 * ty + i;
        if (row < M) {
            float4 o = acc[i];
            if (SCALE) {
                float di = dinv[row];
                o = make_float4(di * o.x, di * o.y, di * o.z, di * o.w);
            }
            *reinterpret_cast<float4*>(C + (size_t)row * 64 + 4 * tx) = o;
        }
    }
}

// One wave per node: out[d] = bias + dinv[d] * (As[d] + sum_s As[s])
// As is pre-scaled by dinv[src]. Each edge = one coalesced 256B wave load.
__global__ __launch_bounds__(256) void k_agg(const float* __restrict__ As,
                                             const int* __restrict__ row_ptr,
                                             const int* __restrict__ csr_src,
                                             const float* __restrict__ dinv,
                                             const float* __restrict__ bias,
                                             float* __restrict__ out, int N) {
    int node = blockIdx.x * 4 + (threadIdx.x >> 6);
    int lane = threadIdx.x & 63;
    if (node >= N) return;
    int beg = row_ptr[node], end = row_ptr[node + 1];
    float acc = As[(size_t)node * 64 + lane];  // self loop (already dinv-scaled)
    for (int p = beg; p < end; p += 64) {
        int m = min(64, end - p);
        int sl = (p + lane < end) ? csr_src[p + lane] : 0;
        int j = 0;
        for (; j + 1 < m; j += 2) {  // 2 independent loads in flight
            int s0 = __shfl(sl, j);
            int s1 = __shfl(sl, j + 1);
            float v0 = As[(size_t)s0 * 64 + lane];
            float v1 = As[(size_t)s1 * 64 + lane];
            acc += v0;
            acc += v1;
        }
        if (j < m) {
            int s0 = __shfl(sl, j);
            acc += As[(size_t)s0 * 64 + lane];
        }
    }
    out[(size_t)node * 64 + lane] = fmaf(dinv[node], acc, bias[lane]);
}

// Edge epilogue: out[e] = relu(Ps[s] + Pd[d] + ea@We + bm1) @ Wm2 + bm2
// 16 lanes per edge (4 edges/wave-pass), 64 edges per wave. No LDS.
__global__ __launch_bounds__(256) void k_edge(
    const float* __restrict__ Ps, const float* __restrict__ Pd,
    const int* __restrict__ src, const int* __restrict__ dst,
    const float* __restrict__ ea, const float* __restrict__ We,
    const float* __restrict__ bm1, const float* __restrict__ Wm2,
    const float* __restrict__ bm2, float* __restrict__ out, int E) {
    const int lane = threadIdx.x & 63;
    const int wid = (blockIdx.x * 256 + threadIdx.x) >> 6;
    const int li = lane & 15, g = lane >> 4;

    float4 wcol[16];  // We[k][4li..4li+3], k=0..15
#pragma unroll
    for (int k = 0; k < 16; k++)
        wcol[k] = *reinterpret_cast<const float4*>(&We[k * 64 + 4 * li]);
    // Wm2 rows c=4li..4li+3 (row-major [64x2])
    float4 w2a = *reinterpret_cast<const float4*>(&Wm2[8 * li]);
    float4 w2b = *reinterpret_cast<const float4*>(&Wm2[8 * li + 4]);
    float4 bb = *reinterpret_cast<const float4*>(&bm1[4 * li]);
    float c0 = bm2[0], c1 = bm2[1];

    const int e0 = wid * 64;
#pragma unroll 2
    for (int pass = 0; pass < 16; pass++) {
        int e = e0 + pass * 4 + g;
        bool ok = (e < E);
        int ec = ok ? e : 0;
        int s = src[ec], d = dst[ec];
        float4 ps = *reinterpret_cast<const float4*>(&Ps[(size_t)s * 64 + 4 * li]);
        float4 pd = *reinterpret_cast<const float4*>(&Pd[(size_t)d * 64 + 4 * li]);
        float ev = ea[(size_t)ec * 16 + li];  // lane li holds ea[e][li]
        float4 q = make_float4(0.f, 0.f, 0.f, 0.f);
#pragma unroll
        for (int k = 0; k < 16; k++) {
            float t = __shfl(ev, (g << 4) + k);
            fma4(q, t, wcol[k]);
        }
        float4 u;
        u.x = fmaxf(ps.x + pd.x + q.x + bb.x, 0.f);
        u.y = fmaxf(ps.y + pd.y + q.y + bb.y, 0.f);
        u.z = fmaxf(ps.z + pd.z + q.z + bb.z, 0.f);
        u.w = fmaxf(ps.w + pd.w + q.w + bb.w, 0.f);
        float p0 = u.x * w2a.x + u.y * w2a.z + u.z * w2b.x + u.w * w2b.z;
        float p1 = u.x * w2a.y + u.y * w2a.w + u.z * w2b.y + u.w * w2b.w;
#pragma unroll
        for (int off = 1; off < 16; off <<= 1) {
            p0 += __shfl_xor(p0, off);
            p1 += __shfl_xor(p1, off);
        }
        if (li == 0 && ok) {
            float2 o = make_float2(p0 + c0, p1 + c1);
            *reinterpret_cast<float2*>(&out[(size_t)e * 2]) = o;
        }
    }
}

static inline size_t align256(size_t x) { return (x + 255) & ~(size_t)255; }

extern "C" void kernel_launch(void* const* d_in, const int* in_sizes, int n_in,
                              void* d_out, int out_size, void* d_ws, size_t ws_size,
                              hipStream_t stream) {
    const float* x = (const float*)d_in[0];
    const int* ei = (const int*)d_in[1];
    const float* ea = (const float*)d_in[2];
    const float* W1 = (const float*)d_in[3];
    const float* b1 = (const float*)d_in[4];
    const float* W2 = (const float*)d_in[5];
    const float* b2 = (const float*)d_in[6];
    const float* Wm1 = (const float*)d_in[7];
    const float* bm1 = (const float*)d_in[8];
    const float* Wm2 = (const float*)d_in[9];
    const float* bm2 = (const float*)d_in[10];

    const int N = in_sizes[0] / 128;  // 50000
    const int E = in_sizes[1] / 2;    // 800000
    const int* src = ei;
    const int* dst = ei + E;
    float* out = (float*)d_out;

    // ws layout (256B-aligned chunks)
    char* p = (char*)d_ws;
    int* cnt = (int*)p;        p += align256((size_t)N * 4);
    int* cur = (int*)p;        p += align256((size_t)N * 4);
    int* row_ptr = (int*)p;    p += align256((size_t)(N + 1) * 4);
    int* csr_src = (int*)p;    p += align256((size_t)E * 4);
    float* dinv = (float*)p;   p += align256((size_t)N * 4);
    float* A = (float*)p;      p += align256((size_t)N * 64 * 4);  // also Ps
    float* B = (float*)p;      p += align256((size_t)N * 64 * 4);
    float* Pd = (float*)p;

    // ---- CSR build (counting sort by dst) ----
    hipMemsetAsync(cnt, 0, (size_t)N * sizeof(int), stream);
    hipMemsetAsync(cur, 0, (size_t)N * sizeof(int), stream);
    k_count<<<(E + 255) / 256, 256, 0, stream>>>(dst, cnt, E);
    k_dinv<<<(N + 255) / 256, 256, 0, stream>>>(cnt, dinv, N);
    k_scan<<<1, 1024, 0, stream>>>(cnt, row_ptr, N);
    k_fill<<<(E + 255) / 256, 256, 0, stream>>>(src, dst, row_ptr, cur, csr_src, E);

    // ---- Layer 1: A = dinv*(x@W1); B = b1 + dinv[d]*(A[d] + sum A[s]) ----
    k_gemm<128, false, true><<<(N + 63) / 64, 256, 0, stream>>>(x, W1, dinv, A, N);
    k_agg<<<(N + 3) / 4, 256, 0, stream>>>(A, row_ptr, csr_src, dinv, b1, B, N);

    // ---- Layer 2 ----
    k_gemm<64, true, true><<<(N + 63) / 64, 256, 0, stream>>>(B, W2, dinv, A, N);
    k_agg<<<(N + 3) / 4, 256, 0, stream>>>(A, row_ptr, csr_src, dinv, b2, B, N);

    // ---- Edge MLP, decomposed ----
    // Ps = relu(h2)@W_s (reuse A), Pd = relu(h2)@W_d; W_s/W_d/W_e = Wm1 rows
    k_gemm<64, true, false><<<(N + 63) / 64, 256, 0, stream>>>(B, Wm1, nullptr, A, N);
    k_gemm<64, true, false><<<(N + 63) / 64, 256, 0, stream>>>(B, Wm1 + 64 * 64,
                                                               nullptr, Pd, N);
    int waves = (E + 63) / 64;
    k_edge<<<(waves + 3) / 4, 256, 0, stream>>>(A, Pd, src, dst, ea,
                                                Wm1 + 128 * 64, bm1, Wm2, bm2,
                                                out, E);
}

// Round 4
// 434.547 us; speedup vs baseline: 14.6233x; 1.1264x over previous
//
#include <hip/hip_runtime.h>
#include <hip/hip_fp16.h>

// ---------------------------------------------------------------------------
// EdgeClassifierGNN: 2x GCNConv (128->64->64, sym-norm, self-loops) + edge MLP
// Round 4:
//  - multi-block prefix scan (old single-block k_scan serialized on 1 CU)
//  - fp16 storage for gather-heavy buffers (agg input A, projections Ps/Pd):
//    halves the 205/410 MB gather streams; accumulate in fp32
//  - fused Ps/Pd projection GEMM (stage relu(h2) tile once)
// ---------------------------------------------------------------------------

__device__ __forceinline__ void fma4(float4& a, float s, const float4& b) {
    a.x = fmaf(s, b.x, a.x);
    a.y = fmaf(s, b.y, a.y);
    a.z = fmaf(s, b.z, a.z);
    a.w = fmaf(s, b.w, a.w);
}

__device__ __forceinline__ float4 relu4(float4 v) {
    v.x = fmaxf(v.x, 0.f); v.y = fmaxf(v.y, 0.f);
    v.z = fmaxf(v.z, 0.f); v.w = fmaxf(v.w, 0.f);
    return v;
}

// store float4 -> 4 contiguous elements at C+idx (fp32 or fp16 variant)
__device__ __forceinline__ void store4(float* C, size_t idx, float4 v) {
    *reinterpret_cast<float4*>(C + idx) = v;
}
__device__ __forceinline__ void store4(__half* C, size_t idx, float4 v) {
    __half2 lo = __floats2half2_rn(v.x, v.y);
    __half2 hi = __floats2half2_rn(v.z, v.w);
    uint2 raw;
    raw.x = *reinterpret_cast<unsigned*>(&lo);
    raw.y = *reinterpret_cast<unsigned*>(&hi);
    *reinterpret_cast<uint2*>(C + idx) = raw;
}

// cnt[d] += 1 per edge (int atomics; self-loop folded into k_dinv)
__global__ void k_count(const int* __restrict__ dst, int* __restrict__ cnt, int E) {
    int e = blockIdx.x * 256 + threadIdx.x;
    if (e < E) atomicAdd(&cnt[dst[e]], 1);
}

// dinv[i] = rsqrt(cnt[i] + 1)
__global__ void k_dinv(const int* __restrict__ cnt, float* __restrict__ dinv, int N) {
    int i = blockIdx.x * 256 + threadIdx.x;
    if (i < N) dinv[i] = rsqrtf((float)cnt[i] + 1.0f);
}

// ---- multi-block exclusive scan: bsum -> scanb -> scan3 ----
__global__ void k_bsum(const int* __restrict__ cnt, int* __restrict__ bsum, int N) {
    int i = blockIdx.x * 256 + threadIdx.x;
    int v = (i < N) ? cnt[i] : 0;
#pragma unroll
    for (int d = 1; d < 64; d <<= 1) v += __shfl_xor(v, d);
    __shared__ int ws[4];
    if ((threadIdx.x & 63) == 0) ws[threadIdx.x >> 6] = v;
    __syncthreads();
    if (threadIdx.x == 0) bsum[blockIdx.x] = ws[0] + ws[1] + ws[2] + ws[3];
}

// in-place exclusive scan of bsum[0..nb), nb <= 256, single block
__global__ void k_scanb(int* __restrict__ bsum, int nb) {
    int t = threadIdx.x;
    int lane = t & 63, w = t >> 6;
    int v = (t < nb) ? bsum[t] : 0;
    int x = v;
#pragma unroll
    for (int d = 1; d < 64; d <<= 1) {
        int y = __shfl_up(x, d);
        if (lane >= d) x += y;
    }
    __shared__ int ws[4];
    if (lane == 63) ws[w] = x;
    __syncthreads();
    int woff = 0;
    for (int j = 0; j < w; j++) woff += ws[j];
    if (t < nb) bsum[t] = woff + x - v;
}

// row_ptr[i] = bsum[blk] + exclusive_scan_within_block(cnt); row_ptr[N] = E
__global__ void k_scan3(const int* __restrict__ cnt, const int* __restrict__ bsum,
                        int* __restrict__ row_ptr, int N, int E) {
    int t = threadIdx.x, b = blockIdx.x;
    int i = b * 256 + t;
    int lane = t & 63, w = t >> 6;
    int v = (i < N) ? cnt[i] : 0;
    int x = v;
#pragma unroll
    for (int d = 1; d < 64; d <<= 1) {
        int y = __shfl_up(x, d);
        if (lane >= d) x += y;
    }
    __shared__ int ws[4];
    if (lane == 63) ws[w] = x;
    __syncthreads();
    int woff = 0;
    for (int j = 0; j < w; j++) woff += ws[j];
    if (i < N) row_ptr[i] = bsum[b] + woff + x - v;
    if (i == 0) row_ptr[N] = E;
}

// csr_src[row_ptr[d] + cur[d]++] = src  (cur pre-zeroed)
__global__ void k_fill(const int* __restrict__ src, const int* __restrict__ dst,
                       const int* __restrict__ row_ptr, int* __restrict__ cur,
                       int* __restrict__ csr_src, int E) {
    int e = blockIdx.x * 256 + threadIdx.x;
    if (e >= E) return;
    int d = dst[e];
    int pos = atomicAdd(&cur[d], 1);
    csr_src[row_ptr[d] + pos] = src[e];
}

// C[M x 64] = (SCALE? dinv[row] : 1) * (op(A[M x K]) @ B[K x 64]); op=relu if RELU_A
template<int K, bool RELU_A, bool SCALE, typename OutT>
__global__ __launch_bounds__(256) void k_gemm(const float* __restrict__ A,
                                              const float* __restrict__ B,
                                              const float* __restrict__ dinv,
                                              OutT* __restrict__ C, int M) {
    constexpr int AS = K + 4;
    __shared__ float As[64 * AS];
    __shared__ float Bs[64 * 64];
    const int t = threadIdx.x;
    const int r0 = blockIdx.x * 64;

    constexpr int C4 = K / 4;  // float4s per A row
    for (int idx = t; idx < 64 * C4; idx += 256) {
        int row = idx / C4, c4 = idx % C4;
        float4 v = make_float4(0.f, 0.f, 0.f, 0.f);
        if (r0 + row < M)
            v = reinterpret_cast<const float4*>(A + (size_t)(r0 + row) * K)[c4];
        if (RELU_A) v = relu4(v);
        *reinterpret_cast<float4*>(&As[row * AS + 4 * c4]) = v;
    }

    const int tx = t & 15, ty = t >> 4;  // 16 cols-of-4 x 16 rows-of-4
    float4 acc[4];
    acc[0] = acc[1] = acc[2] = acc[3] = make_float4(0.f, 0.f, 0.f, 0.f);

    for (int c = 0; c < K / 64; c++) {
        __syncthreads();
        for (int idx = t; idx < 64 * 16; idx += 256)
            reinterpret_cast<float4*>(Bs)[idx] =
                reinterpret_cast<const float4*>(B + (size_t)c * 64 * 64)[idx];
        __syncthreads();
#pragma unroll
        for (int k0 = 0; k0 < 64; k0 += 4) {
            float4 b0 = *reinterpret_cast<const float4*>(&Bs[(k0 + 0) * 64 + 4 * tx]);
            float4 b1 = *reinterpret_cast<const float4*>(&Bs[(k0 + 1) * 64 + 4 * tx]);
            float4 b2 = *reinterpret_cast<const float4*>(&Bs[(k0 + 2) * 64 + 4 * tx]);
            float4 b3 = *reinterpret_cast<const float4*>(&Bs[(k0 + 3) * 64 + 4 * tx]);
#pragma unroll
            for (int i = 0; i < 4; i++) {
                float4 a = *reinterpret_cast<const float4*>(
                    &As[(4 * ty + i) * AS + c * 64 + k0]);
                fma4(acc[i], a.x, b0);
                fma4(acc[i], a.y, b1);
                fma4(acc[i], a.z, b2);
                fma4(acc[i], a.w, b3);
            }
        }
    }

#pragma unroll
    for (int i = 0; i < 4; i++) {
        int row = r0 + 4 * ty + i;
        if (row < M) {
            float4 o = acc[i];
            if (SCALE) {
                float di = dinv[row];
                o = make_float4(di * o.x, di * o.y, di * o.z, di * o.w);
            }
            store4(C, (size_t)row * 64 + 4 * tx, o);
        }
    }
}

// Fused projections: C0 = relu(A)@B0, C1 = relu(A)@B1 (A staged once), fp16 out
__global__ __launch_bounds__(256) void k_proj(const float* __restrict__ A,
                                              const float* __restrict__ B0,
                                              const float* __restrict__ B1,
                                              __half* __restrict__ C0,
                                              __half* __restrict__ C1, int M) {
    constexpr int AS = 68;
    __shared__ float As[64 * AS];
    __shared__ float Bs[64 * 64];
    const int t = threadIdx.x;
    const int r0 = blockIdx.x * 64;

    for (int idx = t; idx < 64 * 16; idx += 256) {
        int row = idx / 16, c4 = idx % 16;
        float4 v = make_float4(0.f, 0.f, 0.f, 0.f);
        if (r0 + row < M)
            v = relu4(reinterpret_cast<const float4*>(A + (size_t)(r0 + row) * 64)[c4]);
        *reinterpret_cast<float4*>(&As[row * AS + 4 * c4]) = v;
    }

    const int tx = t & 15, ty = t >> 4;
    for (int m = 0; m < 2; m++) {
        const float* B = m ? B1 : B0;
        __half* C = m ? C1 : C0;
        __syncthreads();
        for (int idx = t; idx < 64 * 16; idx += 256)
            reinterpret_cast<float4*>(Bs)[idx] =
                reinterpret_cast<const float4*>(B)[idx];
        __syncthreads();
        float4 acc[4];
        acc[0] = acc[1] = acc[2] = acc[3] = make_float4(0.f, 0.f, 0.f, 0.f);
#pragma unroll
        for (int k0 = 0; k0 < 64; k0 += 4) {
            float4 b0 = *reinterpret_cast<const float4*>(&Bs[(k0 + 0) * 64 + 4 * tx]);
            float4 b1 = *reinterpret_cast<const float4*>(&Bs[(k0 + 1) * 64 + 4 * tx]);
            float4 b2 = *reinterpret_cast<const float4*>(&Bs[(k0 + 2) * 64 + 4 * tx]);
            float4 b3 = *reinterpret_cast<const float4*>(&Bs[(k0 + 3) * 64 + 4 * tx]);
#pragma unroll
            for (int i = 0; i < 4; i++) {
                float4 a = *reinterpret_cast<const float4*>(&As[(4 * ty + i) * AS + k0]);
                fma4(acc[i], a.x, b0);
                fma4(acc[i], a.y, b1);
                fma4(acc[i], a.z, b2);
                fma4(acc[i], a.w, b3);
            }
        }
#pragma unroll
        for (int i = 0; i < 4; i++) {
            int row = r0 + 4 * ty + i;
            if (row < M) store4(C, (size_t)row * 64 + 4 * tx, acc[i]);
        }
    }
}

// One wave per node: out[d] = bias + dinv[d] * (A16[d] + sum_s A16[s]); fp16 in
__global__ __launch_bounds__(256) void k_agg(const __half* __restrict__ A16,
                                             const int* __restrict__ row_ptr,
                                             const int* __restrict__ csr_src,
                                             const float* __restrict__ dinv,
                                             const float* __restrict__ bias,
                                             float* __restrict__ out, int N) {
    int node = blockIdx.x * 4 + (threadIdx.x >> 6);
    int lane = threadIdx.x & 63;
    if (node >= N) return;
    int beg = row_ptr[node], end = row_ptr[node + 1];
    float acc = __half2float(A16[(size_t)node * 64 + lane]);  // self loop
    for (int p = beg; p < end; p += 64) {
        int m = min(64, end - p);
        int sl = (p + lane < end) ? csr_src[p + lane] : 0;
        int j = 0;
        for (; j + 1 < m; j += 2) {  // 2 independent loads in flight
            int s0 = __shfl(sl, j);
            int s1 = __shfl(sl, j + 1);
            float v0 = __half2float(A16[(size_t)s0 * 64 + lane]);
            float v1 = __half2float(A16[(size_t)s1 * 64 + lane]);
            acc += v0;
            acc += v1;
        }
        if (j < m) {
            int s0 = __shfl(sl, j);
            acc += __half2float(A16[(size_t)s0 * 64 + lane]);
        }
    }
    out[(size_t)node * 64 + lane] = fmaf(dinv[node], acc, bias[lane]);
}

// Edge epilogue: out[e] = relu(Ps[s] + Pd[d] + ea@We + bm1) @ Wm2 + bm2
// 16 lanes per edge, fp16 gathers (8B/lane), no LDS.
__global__ __launch_bounds__(256) void k_edge(
    const __half* __restrict__ Ps, const __half* __restrict__ Pd,
    const int* __restrict__ src, const int* __restrict__ dst,
    const float* __restrict__ ea, const float* __restrict__ We,
    const float* __restrict__ bm1, const float* __restrict__ Wm2,
    const float* __restrict__ bm2, float* __restrict__ out, int E) {
    const int lane = threadIdx.x & 63;
    const int wid = (blockIdx.x * 256 + threadIdx.x) >> 6;
    const int li = lane & 15, g = lane >> 4;

    float4 wcol[16];  // We[k][4li..4li+3], k=0..15
#pragma unroll
    for (int k = 0; k < 16; k++)
        wcol[k] = *reinterpret_cast<const float4*>(&We[k * 64 + 4 * li]);
    float4 w2a = *reinterpret_cast<const float4*>(&Wm2[8 * li]);
    float4 w2b = *reinterpret_cast<const float4*>(&Wm2[8 * li + 4]);
    float4 bb = *reinterpret_cast<const float4*>(&bm1[4 * li]);
    float c0 = bm2[0], c1 = bm2[1];

    const int e0 = wid * 64;
#pragma unroll 2
    for (int pass = 0; pass < 16; pass++) {
        int e = e0 + pass * 4 + g;
        bool ok = (e < E);
        int ec = ok ? e : 0;
        int s = src[ec], d = dst[ec];
        uint2 rs = *reinterpret_cast<const uint2*>(&Ps[(size_t)s * 64 + 4 * li]);
        uint2 rd = *reinterpret_cast<const uint2*>(&Pd[(size_t)d * 64 + 4 * li]);
        float2 ps0 = __half22float2(*reinterpret_cast<__half2*>(&rs.x));
        float2 ps1 = __half22float2(*reinterpret_cast<__half2*>(&rs.y));
        float2 pd0 = __half22float2(*reinterpret_cast<__half2*>(&rd.x));
        float2 pd1 = __half22float2(*reinterpret_cast<__half2*>(&rd.y));
        float ev = ea[(size_t)ec * 16 + li];  // lane li holds ea[e][li]
        float4 q = make_float4(0.f, 0.f, 0.f, 0.f);
#pragma unroll
        for (int k = 0; k < 16; k++) {
            float t = __shfl(ev, (g << 4) + k);
            fma4(q, t, wcol[k]);
        }
        float4 u;
        u.x = fmaxf(ps0.x + pd0.x + q.x + bb.x, 0.f);
        u.y = fmaxf(ps0.y + pd0.y + q.y + bb.y, 0.f);
        u.z = fmaxf(ps1.x + pd1.x + q.z + bb.z, 0.f);
        u.w = fmaxf(ps1.y + pd1.y + q.w + bb.w, 0.f);
        float p0 = u.x * w2a.x + u.y * w2a.z + u.z * w2b.x + u.w * w2b.z;
        float p1 = u.x * w2a.y + u.y * w2a.w + u.z * w2b.y + u.w * w2b.w;
#pragma unroll
        for (int off = 1; off < 16; off <<= 1) {
            p0 += __shfl_xor(p0, off);
            p1 += __shfl_xor(p1, off);
        }
        if (li == 0 && ok) {
            float2 o = make_float2(p0 + c0, p1 + c1);
            *reinterpret_cast<float2*>(&out[(size_t)e * 2]) = o;
        }
    }
}

static inline size_t align256(size_t x) { return (x + 255) & ~(size_t)255; }

extern "C" void kernel_launch(void* const* d_in, const int* in_sizes, int n_in,
                              void* d_out, int out_size, void* d_ws, size_t ws_size,
                              hipStream_t stream) {
    const float* x = (const float*)d_in[0];
    const int* ei = (const int*)d_in[1];
    const float* ea = (const float*)d_in[2];
    const float* W1 = (const float*)d_in[3];
    const float* b1 = (const float*)d_in[4];
    const float* W2 = (const float*)d_in[5];
    const float* b2 = (const float*)d_in[6];
    const float* Wm1 = (const float*)d_in[7];
    const float* bm1 = (const float*)d_in[8];
    const float* Wm2 = (const float*)d_in[9];
    const float* bm2 = (const float*)d_in[10];

    const int N = in_sizes[0] / 128;  // 50000
    const int E = in_sizes[1] / 2;    // 800000
    const int* src = ei;
    const int* dst = ei + E;
    float* out = (float*)d_out;

    const int NB = (N + 255) / 256;  // scan blocks (196)

    // ws layout (256B-aligned chunks)
    char* p = (char*)d_ws;
    int* cnt = (int*)p;        p += align256((size_t)N * 4);
    int* cur = (int*)p;        p += align256((size_t)N * 4);
    int* row_ptr = (int*)p;    p += align256((size_t)(N + 1) * 4);
    int* bsum = (int*)p;       p += align256((size_t)NB * 4);
    int* csr_src = (int*)p;    p += align256((size_t)E * 4);
    float* dinv = (float*)p;   p += align256((size_t)N * 4);
    __half* A16 = (__half*)p;  p += align256((size_t)N * 64 * 2);
    float* B = (float*)p;      p += align256((size_t)N * 64 * 4);
    __half* Ps16 = (__half*)p; p += align256((size_t)N * 64 * 2);
    __half* Pd16 = (__half*)p;

    // ---- CSR build (counting sort by dst) ----
    hipMemsetAsync(cnt, 0, (size_t)N * sizeof(int), stream);
    hipMemsetAsync(cur, 0, (size_t)N * sizeof(int), stream);
    k_count<<<(E + 255) / 256, 256, 0, stream>>>(dst, cnt, E);
    k_dinv<<<NB, 256, 0, stream>>>(cnt, dinv, N);
    k_bsum<<<NB, 256, 0, stream>>>(cnt, bsum, N);
    k_scanb<<<1, 256, 0, stream>>>(bsum, NB);
    k_scan3<<<NB, 256, 0, stream>>>(cnt, bsum, row_ptr, N, E);
    k_fill<<<(E + 255) / 256, 256, 0, stream>>>(src, dst, row_ptr, cur, csr_src, E);

    // ---- Layer 1: A16 = dinv*(x@W1); B = b1 + dinv[d]*(A16[d] + sum A16[s]) ----
    k_gemm<128, false, true, __half><<<(N + 63) / 64, 256, 0, stream>>>(
        x, W1, dinv, A16, N);
    k_agg<<<(N + 3) / 4, 256, 0, stream>>>(A16, row_ptr, csr_src, dinv, b1, B, N);

    // ---- Layer 2 ----
    k_gemm<64, true, true, __half><<<(N + 63) / 64, 256, 0, stream>>>(
        B, W2, dinv, A16, N);
    k_agg<<<(N + 3) / 4, 256, 0, stream>>>(A16, row_ptr, csr_src, dinv, b2, B, N);

    // ---- Edge MLP, decomposed: Ps/Pd projections fused, then edge epilogue ----
    k_proj<<<(N + 63) / 64, 256, 0, stream>>>(B, Wm1, Wm1 + 64 * 64, Ps16, Pd16, N);
    int waves = (E + 63) / 64;
    k_edge<<<(waves + 3) / 4, 256, 0, stream>>>(Ps16, Pd16, src, dst, ea,
                                                Wm1 + 128 * 64, bm1, Wm2, bm2,
                                                out, E);
}

// Round 5
// 385.276 us; speedup vs baseline: 16.4934x; 1.1279x over previous
//
#include <hip/hip_runtime.h>
#include <hip/hip_fp16.h>

// ---------------------------------------------------------------------------
// EdgeClassifierGNN: 2x GCNConv (128->64->64, sym-norm, self-loops) + edge MLP
// Round 5:
//  - k_edge: hoist indices + ea into registers (coalesced), 4-deep gather
//    pipeline, packed-fp16 ea@We (latency-bound fix; R4 showed not BW-bound)
//  - k_agg: half2 per lane, 2 nodes/wave (halves per-edge issue count)
//  - k_dinv folded into k_bsum
// ---------------------------------------------------------------------------

__device__ __forceinline__ void fma4(float4& a, float s, const float4& b) {
    a.x = fmaf(s, b.x, a.x);
    a.y = fmaf(s, b.y, a.y);
    a.z = fmaf(s, b.z, a.z);
    a.w = fmaf(s, b.w, a.w);
}

__device__ __forceinline__ float4 relu4(float4 v) {
    v.x = fmaxf(v.x, 0.f); v.y = fmaxf(v.y, 0.f);
    v.z = fmaxf(v.z, 0.f); v.w = fmaxf(v.w, 0.f);
    return v;
}

__device__ __forceinline__ void store4(float* C, size_t idx, float4 v) {
    *reinterpret_cast<float4*>(C + idx) = v;
}
__device__ __forceinline__ void store4(__half* C, size_t idx, float4 v) {
    __half2 lo = __floats2half2_rn(v.x, v.y);
    __half2 hi = __floats2half2_rn(v.z, v.w);
    uint2 raw;
    raw.x = *reinterpret_cast<unsigned*>(&lo);
    raw.y = *reinterpret_cast<unsigned*>(&hi);
    *reinterpret_cast<uint2*>(C + idx) = raw;
}

// cnt[d] += 1 per edge (int atomics; self-loop folded into dinv)
__global__ void k_count(const int* __restrict__ dst, int* __restrict__ cnt, int E) {
    int e = blockIdx.x * 256 + threadIdx.x;
    if (e < E) atomicAdd(&cnt[dst[e]], 1);
}

// block sums for scan + dinv = rsqrt(cnt+1) (fused)
__global__ void k_bsum(const int* __restrict__ cnt, int* __restrict__ bsum,
                       float* __restrict__ dinv, int N) {
    int i = blockIdx.x * 256 + threadIdx.x;
    int v = (i < N) ? cnt[i] : 0;
    if (i < N) dinv[i] = rsqrtf((float)v + 1.0f);
    int r = v;
#pragma unroll
    for (int d = 1; d < 64; d <<= 1) r += __shfl_xor(r, d);
    __shared__ int ws[4];
    if ((threadIdx.x & 63) == 0) ws[threadIdx.x >> 6] = r;
    __syncthreads();
    if (threadIdx.x == 0) bsum[blockIdx.x] = ws[0] + ws[1] + ws[2] + ws[3];
}

// in-place exclusive scan of bsum[0..nb), nb <= 256, single block
__global__ void k_scanb(int* __restrict__ bsum, int nb) {
    int t = threadIdx.x;
    int lane = t & 63, w = t >> 6;
    int v = (t < nb) ? bsum[t] : 0;
    int x = v;
#pragma unroll
    for (int d = 1; d < 64; d <<= 1) {
        int y = __shfl_up(x, d);
        if (lane >= d) x += y;
    }
    __shared__ int ws[4];
    if (lane == 63) ws[w] = x;
    __syncthreads();
    int woff = 0;
    for (int j = 0; j < w; j++) woff += ws[j];
    if (t < nb) bsum[t] = woff + x - v;
}

// row_ptr[i] = bsum[blk] + exclusive_scan_within_block(cnt); row_ptr[N] = E
__global__ void k_scan3(const int* __restrict__ cnt, const int* __restrict__ bsum,
                        int* __restrict__ row_ptr, int N, int E) {
    int t = threadIdx.x, b = blockIdx.x;
    int i = b * 256 + t;
    int lane = t & 63, w = t >> 6;
    int v = (i < N) ? cnt[i] : 0;
    int x = v;
#pragma unroll
    for (int d = 1; d < 64; d <<= 1) {
        int y = __shfl_up(x, d);
        if (lane >= d) x += y;
    }
    __shared__ int ws[4];
    if (lane == 63) ws[w] = x;
    __syncthreads();
    int woff = 0;
    for (int j = 0; j < w; j++) woff += ws[j];
    if (i < N) row_ptr[i] = bsum[b] + woff + x - v;
    if (i == 0) row_ptr[N] = E;
}

// csr_src[row_ptr[d] + cur[d]++] = src  (cur pre-zeroed)
__global__ void k_fill(const int* __restrict__ src, const int* __restrict__ dst,
                       const int* __restrict__ row_ptr, int* __restrict__ cur,
                       int* __restrict__ csr_src, int E) {
    int e = blockIdx.x * 256 + threadIdx.x;
    if (e >= E) return;
    int d = dst[e];
    int pos = atomicAdd(&cur[d], 1);
    csr_src[row_ptr[d] + pos] = src[e];
}

// C[M x 64] = (SCALE? dinv[row] : 1) * (op(A[M x K]) @ B[K x 64]); op=relu if RELU_A
template<int K, bool RELU_A, bool SCALE, typename OutT>
__global__ __launch_bounds__(256) void k_gemm(const float* __restrict__ A,
                                              const float* __restrict__ B,
                                              const float* __restrict__ dinv,
                                              OutT* __restrict__ C, int M) {
    constexpr int AS = K + 4;
    __shared__ float As[64 * AS];
    __shared__ float Bs[64 * 64];
    const int t = threadIdx.x;
    const int r0 = blockIdx.x * 64;

    constexpr int C4 = K / 4;
    for (int idx = t; idx < 64 * C4; idx += 256) {
        int row = idx / C4, c4 = idx % C4;
        float4 v = make_float4(0.f, 0.f, 0.f, 0.f);
        if (r0 + row < M)
            v = reinterpret_cast<const float4*>(A + (size_t)(r0 + row) * K)[c4];
        if (RELU_A) v = relu4(v);
        *reinterpret_cast<float4*>(&As[row * AS + 4 * c4]) = v;
    }

    const int tx = t & 15, ty = t >> 4;
    float4 acc[4];
    acc[0] = acc[1] = acc[2] = acc[3] = make_float4(0.f, 0.f, 0.f, 0.f);

    for (int c = 0; c < K / 64; c++) {
        __syncthreads();
        for (int idx = t; idx < 64 * 16; idx += 256)
            reinterpret_cast<float4*>(Bs)[idx] =
                reinterpret_cast<const float4*>(B + (size_t)c * 64 * 64)[idx];
        __syncthreads();
#pragma unroll
        for (int k0 = 0; k0 < 64; k0 += 4) {
            float4 b0 = *reinterpret_cast<const float4*>(&Bs[(k0 + 0) * 64 + 4 * tx]);
            float4 b1 = *reinterpret_cast<const float4*>(&Bs[(k0 + 1) * 64 + 4 * tx]);
            float4 b2 = *reinterpret_cast<const float4*>(&Bs[(k0 + 2) * 64 + 4 * tx]);
            float4 b3 = *reinterpret_cast<const float4*>(&Bs[(k0 + 3) * 64 + 4 * tx]);
#pragma unroll
            for (int i = 0; i < 4; i++) {
                float4 a = *reinterpret_cast<const float4*>(
                    &As[(4 * ty + i) * AS + c * 64 + k0]);
                fma4(acc[i], a.x, b0);
                fma4(acc[i], a.y, b1);
                fma4(acc[i], a.z, b2);
                fma4(acc[i], a.w, b3);
            }
        }
    }

#pragma unroll
    for (int i = 0; i < 4; i++) {
        int row = r0 + 4 * ty + i;
        if (row < M) {
            float4 o = acc[i];
            if (SCALE) {
                float di = dinv[row];
                o = make_float4(di * o.x, di * o.y, di * o.z, di * o.w);
            }
            store4(C, (size_t)row * 64 + 4 * tx, o);
        }
    }
}

// Fused projections: C0 = relu(A)@B0, C1 = relu(A)@B1 (A staged once), fp16 out
__global__ __launch_bounds__(256) void k_proj(const float* __restrict__ A,
                                              const float* __restrict__ B0,
                                              const float* __restrict__ B1,
                                              __half* __restrict__ C0,
                                              __half* __restrict__ C1, int M) {
    constexpr int AS = 68;
    __shared__ float As[64 * AS];
    __shared__ float Bs[64 * 64];
    const int t = threadIdx.x;
    const int r0 = blockIdx.x * 64;

    for (int idx = t; idx < 64 * 16; idx += 256) {
        int row = idx / 16, c4 = idx % 16;
        float4 v = make_float4(0.f, 0.f, 0.f, 0.f);
        if (r0 + row < M)
            v = relu4(reinterpret_cast<const float4*>(A + (size_t)(r0 + row) * 64)[c4]);
        *reinterpret_cast<float4*>(&As[row * AS + 4 * c4]) = v;
    }

    const int tx = t & 15, ty = t >> 4;
    for (int m = 0; m < 2; m++) {
        const float* B = m ? B1 : B0;
        __half* C = m ? C1 : C0;
        __syncthreads();
        for (int idx = t; idx < 64 * 16; idx += 256)
            reinterpret_cast<float4*>(Bs)[idx] =
                reinterpret_cast<const float4*>(B)[idx];
        __syncthreads();
        float4 acc[4];
        acc[0] = acc[1] = acc[2] = acc[3] = make_float4(0.f, 0.f, 0.f, 0.f);
#pragma unroll
        for (int k0 = 0; k0 < 64; k0 += 4) {
            float4 b0 = *reinterpret_cast<const float4*>(&Bs[(k0 + 0) * 64 + 4 * tx]);
            float4 b1 = *reinterpret_cast<const float4*>(&Bs[(k0 + 1) * 64 + 4 * tx]);
            float4 b2 = *reinterpret_cast<const float4*>(&Bs[(k0 + 2) * 64 + 4 * tx]);
            float4 b3 = *reinterpret_cast<const float4*>(&Bs[(k0 + 3) * 64 + 4 * tx]);
#pragma unroll
            for (int i = 0; i < 4; i++) {
                float4 a = *reinterpret_cast<const float4*>(&As[(4 * ty + i) * AS + k0]);
                fma4(acc[i], a.x, b0);
                fma4(acc[i], a.y, b1);
                fma4(acc[i], a.z, b2);
                fma4(acc[i], a.w, b3);
            }
        }
#pragma unroll
        for (int i = 0; i < 4; i++) {
            int row = r0 + 4 * ty + i;
            if (row < M) store4(C, (size_t)row * 64 + 4 * tx, acc[i]);
        }
    }
}

// 2 nodes/wave, half2 per lane: out[d] = bias + dinv[d]*(A16[d] + sum_s A16[s])
__global__ __launch_bounds__(256) void k_agg(const __half* __restrict__ A16,
                                             const int* __restrict__ row_ptr,
                                             const int* __restrict__ csr_src,
                                             const float* __restrict__ dinv,
                                             const float* __restrict__ bias,
                                             float* __restrict__ out, int N) {
    int gw = (blockIdx.x * 256 + threadIdx.x) >> 6;
    int sub = (threadIdx.x >> 5) & 1;
    int l = threadIdx.x & 31;
    int node = gw * 2 + sub;
    if (node >= N) return;
    int beg = row_ptr[node], end = row_ptr[node + 1];
    const __half2* A2 = reinterpret_cast<const __half2*>(A16);
    float2 acc = __half22float2(A2[(size_t)node * 32 + l]);  // self loop
    for (int p = beg; p < end; p += 32) {
        int m = min(32, end - p);
        int sl = (p + l < end) ? csr_src[p + l] : 0;
        int j = 0;
        for (; j + 1 < m; j += 2) {
            int s0 = __shfl(sl, j, 32);
            int s1 = __shfl(sl, j + 1, 32);
            float2 v0 = __half22float2(A2[(size_t)s0 * 32 + l]);
            float2 v1 = __half22float2(A2[(size_t)s1 * 32 + l]);
            acc.x += v0.x + v1.x;
            acc.y += v0.y + v1.y;
        }
        if (j < m) {
            int s0 = __shfl(sl, j, 32);
            float2 v0 = __half22float2(A2[(size_t)s0 * 32 + l]);
            acc.x += v0.x;
            acc.y += v0.y;
        }
    }
    float di = dinv[node];
    float2 bb = *reinterpret_cast<const float2*>(&bias[2 * l]);
    float2 o = make_float2(fmaf(di, acc.x, bb.x), fmaf(di, acc.y, bb.y));
    *reinterpret_cast<float2*>(&out[(size_t)node * 64 + 2 * l]) = o;
}

// Edge epilogue: out[e] = relu(Ps[s] + Pd[d] + ea@We + bm1) @ Wm2 + bm2
// Per wave: 64 edges. Indices + ea hoisted to registers (coalesced loads),
// 4-deep gather pipeline, packed-fp16 ea@We.
__global__ __launch_bounds__(256) void k_edge(
    const __half* __restrict__ Ps, const __half* __restrict__ Pd,
    const int* __restrict__ src, const int* __restrict__ dst,
    const float* __restrict__ ea, const float* __restrict__ We,
    const float* __restrict__ bm1, const float* __restrict__ Wm2,
    const float* __restrict__ bm2, float* __restrict__ out, int E) {
    const int lane = threadIdx.x & 63;
    const int wid = (blockIdx.x * 256 + threadIdx.x) >> 6;
    const int li = lane & 15, g = lane >> 4;
    const int e0 = wid * 64;
    if (e0 >= E) return;

    // We cols 4li..4li+3 as packed fp16: wc[k][j] = (We[k][4li+2j], [4li+2j+1])
    __half2 wc[16][2];
#pragma unroll
    for (int k = 0; k < 16; k++) {
        float4 w = *reinterpret_cast<const float4*>(&We[k * 64 + 4 * li]);
        wc[k][0] = __floats2half2_rn(w.x, w.y);
        wc[k][1] = __floats2half2_rn(w.z, w.w);
    }
    float4 w2a = *reinterpret_cast<const float4*>(&Wm2[8 * li]);
    float4 w2b = *reinterpret_cast<const float4*>(&Wm2[8 * li + 4]);
    float4 bb = *reinterpret_cast<const float4*>(&bm1[4 * li]);
    float c0 = bm2[0], c1 = bm2[1];

    // hoist 64 edge indices (coalesced)
    int ecl = min(e0 + lane, E - 1);
    int sv = src[ecl], dv = dst[ecl];

    // hoist ea for 64 edges: 1024 floats/wave -> 8 half2/lane
    // chunk j: lane holds pairs P = 128j+2*lane (+1); pair P = ea halves 2P,2P+1
    int hzi[8];
    size_t eabase = (size_t)e0 * 16;
    size_t eamax = (size_t)E * 16 - 4;
#pragma unroll
    for (int j = 0; j < 4; j++) {
        size_t off = eabase + 256 * j + 4 * lane;
        float4 f = *reinterpret_cast<const float4*>(ea + min(off, eamax));
        __half2 a = __floats2half2_rn(f.x, f.y);
        __half2 b = __floats2half2_rn(f.z, f.w);
        hzi[2 * j] = *reinterpret_cast<int*>(&a);
        hzi[2 * j + 1] = *reinterpret_cast<int*>(&b);
    }

    uint2 rs[4], rd[4];
#define ISSUE(p, slot)                                                      \
    {                                                                       \
        int idx = 4 * (p) + g;                                              \
        int s = __shfl(sv, idx);                                            \
        int d = __shfl(dv, idx);                                            \
        rs[slot] = *reinterpret_cast<const uint2*>(&Ps[(size_t)s * 64 + 4 * li]); \
        rd[slot] = *reinterpret_cast<const uint2*>(&Pd[(size_t)d * 64 + 4 * li]); \
    }
    ISSUE(0, 0) ISSUE(1, 1) ISSUE(2, 2) ISSUE(3, 3)

#pragma unroll
    for (int p = 0; p < 16; p++) {
        const int slot = p & 3;
        uint2 crs = rs[slot], crd = rd[slot];
        if (p + 4 < 16) ISSUE(p + 4, slot)

        // q = ea[e] @ We (packed fp16); pair P = 32p+8g+m, m=0..7
        __half2 q0 = __floats2half2_rn(0.f, 0.f);
        __half2 q1 = q0;
#pragma unroll
        for (int m = 0; m < 8; m++) {
            int srcl = 16 * (p & 3) + 4 * g + (m >> 1);
            int u = __shfl(hzi[2 * (p >> 2) + (m & 1)], srcl);
            __half2 tt = *reinterpret_cast<__half2*>(&u);
            __half2 t0 = __low2half2(tt);
            __half2 t1 = __high2half2(tt);
            q0 = __hfma2(t0, wc[2 * m][0], q0);
            q1 = __hfma2(t0, wc[2 * m][1], q1);
            q0 = __hfma2(t1, wc[2 * m + 1][0], q0);
            q1 = __hfma2(t1, wc[2 * m + 1][1], q1);
        }
        float2 q0f = __half22float2(q0);
        float2 q1f = __half22float2(q1);

        float2 ps0 = __half22float2(*reinterpret_cast<__half2*>(&crs.x));
        float2 ps1 = __half22float2(*reinterpret_cast<__half2*>(&crs.y));
        float2 pd0 = __half22float2(*reinterpret_cast<__half2*>(&crd.x));
        float2 pd1 = __half22float2(*reinterpret_cast<__half2*>(&crd.y));

        float4 u4;
        u4.x = fmaxf(ps0.x + pd0.x + q0f.x + bb.x, 0.f);
        u4.y = fmaxf(ps0.y + pd0.y + q0f.y + bb.y, 0.f);
        u4.z = fmaxf(ps1.x + pd1.x + q1f.x + bb.z, 0.f);
        u4.w = fmaxf(ps1.y + pd1.y + q1f.y + bb.w, 0.f);
        float p0 = u4.x * w2a.x + u4.y * w2a.z + u4.z * w2b.x + u4.w * w2b.z;
        float p1 = u4.x * w2a.y + u4.y * w2a.w + u4.z * w2b.y + u4.w * w2b.w;
#pragma unroll
        for (int off = 1; off < 16; off <<= 1) {
            p0 += __shfl_xor(p0, off);
            p1 += __shfl_xor(p1, off);
        }
        int e = e0 + 4 * p + g;
        if (li == 0 && e < E) {
            float2 o = make_float2(p0 + c0, p1 + c1);
            *reinterpret_cast<float2*>(&out[(size_t)e * 2]) = o;
        }
    }
#undef ISSUE
}

static inline size_t align256(size_t x) { return (x + 255) & ~(size_t)255; }

extern "C" void kernel_launch(void* const* d_in, const int* in_sizes, int n_in,
                              void* d_out, int out_size, void* d_ws, size_t ws_size,
                              hipStream_t stream) {
    const float* x = (const float*)d_in[0];
    const int* ei = (const int*)d_in[1];
    const float* ea = (const float*)d_in[2];
    const float* W1 = (const float*)d_in[3];
    const float* b1 = (const float*)d_in[4];
    const float* W2 = (const float*)d_in[5];
    const float* b2 = (const float*)d_in[6];
    const float* Wm1 = (const float*)d_in[7];
    const float* bm1 = (const float*)d_in[8];
    const float* Wm2 = (const float*)d_in[9];
    const float* bm2 = (const float*)d_in[10];

    const int N = in_sizes[0] / 128;  // 50000
    const int E = in_sizes[1] / 2;    // 800000
    const int* src = ei;
    const int* dst = ei + E;
    float* out = (float*)d_out;

    const int NB = (N + 255) / 256;  // scan blocks (196)

    // ws layout (256B-aligned chunks)
    char* p = (char*)d_ws;
    int* cnt = (int*)p;        p += align256((size_t)N * 4);
    int* cur = (int*)p;        p += align256((size_t)N * 4);
    int* row_ptr = (int*)p;    p += align256((size_t)(N + 1) * 4);
    int* bsum = (int*)p;       p += align256((size_t)NB * 4);
    int* csr_src = (int*)p;    p += align256((size_t)E * 4);
    float* dinv = (float*)p;   p += align256((size_t)N * 4);
    __half* A16 = (__half*)p;  p += align256((size_t)N * 64 * 2);
    float* B = (float*)p;      p += align256((size_t)N * 64 * 4);
    __half* Ps16 = (__half*)p; p += align256((size_t)N * 64 * 2);
    __half* Pd16 = (__half*)p;

    // ---- CSR build (counting sort by dst) ----
    hipMemsetAsync(cnt, 0, (size_t)N * sizeof(int), stream);
    hipMemsetAsync(cur, 0, (size_t)N * sizeof(int), stream);
    k_count<<<(E + 255) / 256, 256, 0, stream>>>(dst, cnt, E);
    k_bsum<<<NB, 256, 0, stream>>>(cnt, bsum, dinv, N);
    k_scanb<<<1, 256, 0, stream>>>(bsum, NB);
    k_scan3<<<NB, 256, 0, stream>>>(cnt, bsum, row_ptr, N, E);
    k_fill<<<(E + 255) / 256, 256, 0, stream>>>(src, dst, row_ptr, cur, csr_src, E);

    // ---- Layer 1 ----
    k_gemm<128, false, true, __half><<<(N + 63) / 64, 256, 0, stream>>>(
        x, W1, dinv, A16, N);
    k_agg<<<(N + 7) / 8, 256, 0, stream>>>(A16, row_ptr, csr_src, dinv, b1, B, N);

    // ---- Layer 2 ----
    k_gemm<64, true, true, __half><<<(N + 63) / 64, 256, 0, stream>>>(
        B, W2, dinv, A16, N);
    k_agg<<<(N + 7) / 8, 256, 0, stream>>>(A16, row_ptr, csr_src, dinv, b2, B, N);

    // ---- Edge MLP, decomposed ----
    k_proj<<<(N + 63) / 64, 256, 0, stream>>>(B, Wm1, Wm1 + 64 * 64, Ps16, Pd16, N);
    int waves = (E + 63) / 64;
    k_edge<<<(waves + 3) / 4, 256, 0, stream>>>(Ps16, Pd16, src, dst, ea,
                                                Wm1 + 128 * 64, bm1, Wm2, bm2,
                                                out, E);
}

// Round 6
// 352.605 us; speedup vs baseline: 18.0216x; 1.0927x over previous
//
#include <hip/hip_runtime.h>
#include <hip/hip_fp16.h>

// ---------------------------------------------------------------------------
// EdgeClassifierGNN: 2x GCNConv (128->64->64, sym-norm, self-loops) + edge MLP
// Round 6:
//  - CSR build: rank[] recorded in k_count -> k_fill is atomic-free scatter
//  - k_agg: 16 lanes/node (4x fp16), 4 nodes/wave, 4-deep gather pipeline
//  - k_edge: 8-deep gather pipeline (16 loads in flight/wave)
// ---------------------------------------------------------------------------

__device__ __forceinline__ void fma4(float4& a, float s, const float4& b) {
    a.x = fmaf(s, b.x, a.x);
    a.y = fmaf(s, b.y, a.y);
    a.z = fmaf(s, b.z, a.z);
    a.w = fmaf(s, b.w, a.w);
}

__device__ __forceinline__ float4 relu4(float4 v) {
    v.x = fmaxf(v.x, 0.f); v.y = fmaxf(v.y, 0.f);
    v.z = fmaxf(v.z, 0.f); v.w = fmaxf(v.w, 0.f);
    return v;
}

__device__ __forceinline__ void store4(float* C, size_t idx, float4 v) {
    *reinterpret_cast<float4*>(C + idx) = v;
}
__device__ __forceinline__ void store4(__half* C, size_t idx, float4 v) {
    __half2 lo = __floats2half2_rn(v.x, v.y);
    __half2 hi = __floats2half2_rn(v.z, v.w);
    uint2 raw;
    raw.x = *reinterpret_cast<unsigned*>(&lo);
    raw.y = *reinterpret_cast<unsigned*>(&hi);
    *reinterpret_cast<uint2*>(C + idx) = raw;
}

// cnt[d]++ per edge; rank[e] = arrival order of e within its dst bucket
__global__ void k_count(const int* __restrict__ dst, int* __restrict__ cnt,
                        int* __restrict__ rank, int E) {
    int e = blockIdx.x * 256 + threadIdx.x;
    if (e < E) rank[e] = atomicAdd(&cnt[dst[e]], 1);
}

// block sums for scan + dinv = rsqrt(cnt+1) (fused)
__global__ void k_bsum(const int* __restrict__ cnt, int* __restrict__ bsum,
                       float* __restrict__ dinv, int N) {
    int i = blockIdx.x * 256 + threadIdx.x;
    int v = (i < N) ? cnt[i] : 0;
    if (i < N) dinv[i] = rsqrtf((float)v + 1.0f);
    int r = v;
#pragma unroll
    for (int d = 1; d < 64; d <<= 1) r += __shfl_xor(r, d);
    __shared__ int ws[4];
    if ((threadIdx.x & 63) == 0) ws[threadIdx.x >> 6] = r;
    __syncthreads();
    if (threadIdx.x == 0) bsum[blockIdx.x] = ws[0] + ws[1] + ws[2] + ws[3];
}

// in-place exclusive scan of bsum[0..nb), nb <= 256, single block
__global__ void k_scanb(int* __restrict__ bsum, int nb) {
    int t = threadIdx.x;
    int lane = t & 63, w = t >> 6;
    int v = (t < nb) ? bsum[t] : 0;
    int x = v;
#pragma unroll
    for (int d = 1; d < 64; d <<= 1) {
        int y = __shfl_up(x, d);
        if (lane >= d) x += y;
    }
    __shared__ int ws[4];
    if (lane == 63) ws[w] = x;
    __syncthreads();
    int woff = 0;
    for (int j = 0; j < w; j++) woff += ws[j];
    if (t < nb) bsum[t] = woff + x - v;
}

// row_ptr[i] = bsum[blk] + exclusive_scan_within_block(cnt); row_ptr[N] = E
__global__ void k_scan3(const int* __restrict__ cnt, const int* __restrict__ bsum,
                        int* __restrict__ row_ptr, int N, int E) {
    int t = threadIdx.x, b = blockIdx.x;
    int i = b * 256 + t;
    int lane = t & 63, w = t >> 6;
    int v = (i < N) ? cnt[i] : 0;
    int x = v;
#pragma unroll
    for (int d = 1; d < 64; d <<= 1) {
        int y = __shfl_up(x, d);
        if (lane >= d) x += y;
    }
    __shared__ int ws[4];
    if (lane == 63) ws[w] = x;
    __syncthreads();
    int woff = 0;
    for (int j = 0; j < w; j++) woff += ws[j];
    if (i < N) row_ptr[i] = bsum[b] + woff + x - v;
    if (i == 0) row_ptr[N] = E;
}

// atomic-free: csr_src[row_ptr[dst[e]] + rank[e]] = src[e]
__global__ void k_fill(const int* __restrict__ src, const int* __restrict__ dst,
                       const int* __restrict__ row_ptr, const int* __restrict__ rank,
                       int* __restrict__ csr_src, int E) {
    int e = blockIdx.x * 256 + threadIdx.x;
    if (e >= E) return;
    csr_src[row_ptr[dst[e]] + rank[e]] = src[e];
}

// C[M x 64] = (SCALE? dinv[row] : 1) * (op(A[M x K]) @ B[K x 64]); op=relu if RELU_A
template<int K, bool RELU_A, bool SCALE, typename OutT>
__global__ __launch_bounds__(256) void k_gemm(const float* __restrict__ A,
                                              const float* __restrict__ B,
                                              const float* __restrict__ dinv,
                                              OutT* __restrict__ C, int M) {
    constexpr int AS = K + 4;
    __shared__ float As[64 * AS];
    __shared__ float Bs[64 * 64];
    const int t = threadIdx.x;
    const int r0 = blockIdx.x * 64;

    constexpr int C4 = K / 4;
    for (int idx = t; idx < 64 * C4; idx += 256) {
        int row = idx / C4, c4 = idx % C4;
        float4 v = make_float4(0.f, 0.f, 0.f, 0.f);
        if (r0 + row < M)
            v = reinterpret_cast<const float4*>(A + (size_t)(r0 + row) * K)[c4];
        if (RELU_A) v = relu4(v);
        *reinterpret_cast<float4*>(&As[row * AS + 4 * c4]) = v;
    }

    const int tx = t & 15, ty = t >> 4;
    float4 acc[4];
    acc[0] = acc[1] = acc[2] = acc[3] = make_float4(0.f, 0.f, 0.f, 0.f);

    for (int c = 0; c < K / 64; c++) {
        __syncthreads();
        for (int idx = t; idx < 64 * 16; idx += 256)
            reinterpret_cast<float4*>(Bs)[idx] =
                reinterpret_cast<const float4*>(B + (size_t)c * 64 * 64)[idx];
        __syncthreads();
#pragma unroll
        for (int k0 = 0; k0 < 64; k0 += 4) {
            float4 b0 = *reinterpret_cast<const float4*>(&Bs[(k0 + 0) * 64 + 4 * tx]);
            float4 b1 = *reinterpret_cast<const float4*>(&Bs[(k0 + 1) * 64 + 4 * tx]);
            float4 b2 = *reinterpret_cast<const float4*>(&Bs[(k0 + 2) * 64 + 4 * tx]);
            float4 b3 = *reinterpret_cast<const float4*>(&Bs[(k0 + 3) * 64 + 4 * tx]);
#pragma unroll
            for (int i = 0; i < 4; i++) {
                float4 a = *reinterpret_cast<const float4*>(
                    &As[(4 * ty + i) * AS + c * 64 + k0]);
                fma4(acc[i], a.x, b0);
                fma4(acc[i], a.y, b1);
                fma4(acc[i], a.z, b2);
                fma4(acc[i], a.w, b3);
            }
        }
    }

#pragma unroll
    for (int i = 0; i < 4; i++) {
        int row = r0 + 4 * ty + i;
        if (row < M) {
            float4 o = acc[i];
            if (SCALE) {
                float di = dinv[row];
                o = make_float4(di * o.x, di * o.y, di * o.z, di * o.w);
            }
            store4(C, (size_t)row * 64 + 4 * tx, o);
        }
    }
}

// Fused projections: C0 = relu(A)@B0, C1 = relu(A)@B1 (A staged once), fp16 out
__global__ __launch_bounds__(256) void k_proj(const float* __restrict__ A,
                                              const float* __restrict__ B0,
                                              const float* __restrict__ B1,
                                              __half* __restrict__ C0,
                                              __half* __restrict__ C1, int M) {
    constexpr int AS = 68;
    __shared__ float As[64 * AS];
    __shared__ float Bs[64 * 64];
    const int t = threadIdx.x;
    const int r0 = blockIdx.x * 64;

    for (int idx = t; idx < 64 * 16; idx += 256) {
        int row = idx / 16, c4 = idx % 16;
        float4 v = make_float4(0.f, 0.f, 0.f, 0.f);
        if (r0 + row < M)
            v = relu4(reinterpret_cast<const float4*>(A + (size_t)(r0 + row) * 64)[c4]);
        *reinterpret_cast<float4*>(&As[row * AS + 4 * c4]) = v;
    }

    const int tx = t & 15, ty = t >> 4;
    for (int m = 0; m < 2; m++) {
        const float* B = m ? B1 : B0;
        __half* C = m ? C1 : C0;
        __syncthreads();
        for (int idx = t; idx < 64 * 16; idx += 256)
            reinterpret_cast<float4*>(Bs)[idx] =
                reinterpret_cast<const float4*>(B)[idx];
        __syncthreads();
        float4 acc[4];
        acc[0] = acc[1] = acc[2] = acc[3] = make_float4(0.f, 0.f, 0.f, 0.f);
#pragma unroll
        for (int k0 = 0; k0 < 64; k0 += 4) {
            float4 b0 = *reinterpret_cast<const float4*>(&Bs[(k0 + 0) * 64 + 4 * tx]);
            float4 b1 = *reinterpret_cast<const float4*>(&Bs[(k0 + 1) * 64 + 4 * tx]);
            float4 b2 = *reinterpret_cast<const float4*>(&Bs[(k0 + 2) * 64 + 4 * tx]);
            float4 b3 = *reinterpret_cast<const float4*>(&Bs[(k0 + 3) * 64 + 4 * tx]);
#pragma unroll
            for (int i = 0; i < 4; i++) {
                float4 a = *reinterpret_cast<const float4*>(&As[(4 * ty + i) * AS + k0]);
                fma4(acc[i], a.x, b0);
                fma4(acc[i], a.y, b1);
                fma4(acc[i], a.z, b2);
                fma4(acc[i], a.w, b3);
            }
        }
#pragma unroll
        for (int i = 0; i < 4; i++) {
            int row = r0 + 4 * ty + i;
            if (row < M) store4(C, (size_t)row * 64 + 4 * tx, acc[i]);
        }
    }
}

// 4 nodes/wave, 16 lanes/node, uint2 (4 fp16)/lane, 4-deep gather pipeline:
// out[d] = bias + dinv[d]*(A16[d] + sum_s A16[s])
__global__ __launch_bounds__(256) void k_agg(const __half* __restrict__ A16,
                                             const int* __restrict__ row_ptr,
                                             const int* __restrict__ csr_src,
                                             const float* __restrict__ dinv,
                                             const float* __restrict__ bias,
                                             float* __restrict__ out, int N) {
    int gw = (blockIdx.x * 256 + threadIdx.x) >> 6;  // global wave
    int sub = (threadIdx.x >> 4) & 3;
    int l = threadIdx.x & 15;
    int node = gw * 4 + sub;
    if (node >= N) return;
    const uint2* A4 = reinterpret_cast<const uint2*>(A16);  // row = 16 uint2

    int beg = row_ptr[node], end = row_ptr[node + 1];
    uint2 selfv = A4[(size_t)node * 16 + l];
    float2 a0 = __half22float2(*reinterpret_cast<__half2*>(&selfv.x));
    float2 a1 = __half22float2(*reinterpret_cast<__half2*>(&selfv.y));
    float4 acc = make_float4(a0.x, a0.y, a1.x, a1.y);

    for (int p = beg; p < end; p += 16) {
        int m = min(16, end - p);
        int sl = (p + l < end) ? csr_src[p + l] : 0;
        int j = 0;
        for (; j + 3 < m; j += 4) {
            int s0 = __shfl(sl, j + 0, 16);
            int s1 = __shfl(sl, j + 1, 16);
            int s2 = __shfl(sl, j + 2, 16);
            int s3 = __shfl(sl, j + 3, 16);
            uint2 u0 = A4[(size_t)s0 * 16 + l];
            uint2 u1 = A4[(size_t)s1 * 16 + l];
            uint2 u2 = A4[(size_t)s2 * 16 + l];
            uint2 u3 = A4[(size_t)s3 * 16 + l];
#define ACC(u)                                                          \
    {                                                                   \
        float2 f0 = __half22float2(*reinterpret_cast<__half2*>(&u.x));  \
        float2 f1 = __half22float2(*reinterpret_cast<__half2*>(&u.y));  \
        acc.x += f0.x; acc.y += f0.y; acc.z += f1.x; acc.w += f1.y;     \
    }
            ACC(u0) ACC(u1) ACC(u2) ACC(u3)
        }
        for (; j < m; j++) {
            int s0 = __shfl(sl, j, 16);
            uint2 u0 = A4[(size_t)s0 * 16 + l];
            ACC(u0)
        }
#undef ACC
    }
    float di = dinv[node];
    float4 bb = *reinterpret_cast<const float4*>(&bias[4 * l]);
    float4 o = make_float4(fmaf(di, acc.x, bb.x), fmaf(di, acc.y, bb.y),
                           fmaf(di, acc.z, bb.z), fmaf(di, acc.w, bb.w));
    *reinterpret_cast<float4*>(&out[(size_t)node * 64 + 4 * l]) = o;
}

// Edge epilogue: out[e] = relu(Ps[s] + Pd[d] + ea@We + bm1) @ Wm2 + bm2
// Per wave: 64 edges. Indices + ea hoisted, 8-deep gather pipeline,
// packed-fp16 ea@We.
__global__ __launch_bounds__(256) void k_edge(
    const __half* __restrict__ Ps, const __half* __restrict__ Pd,
    const int* __restrict__ src, const int* __restrict__ dst,
    const float* __restrict__ ea, const float* __restrict__ We,
    const float* __restrict__ bm1, const float* __restrict__ Wm2,
    const float* __restrict__ bm2, float* __restrict__ out, int E) {
    const int lane = threadIdx.x & 63;
    const int wid = (blockIdx.x * 256 + threadIdx.x) >> 6;
    const int li = lane & 15, g = lane >> 4;
    const int e0 = wid * 64;
    if (e0 >= E) return;

    __half2 wc[16][2];
#pragma unroll
    for (int k = 0; k < 16; k++) {
        float4 w = *reinterpret_cast<const float4*>(&We[k * 64 + 4 * li]);
        wc[k][0] = __floats2half2_rn(w.x, w.y);
        wc[k][1] = __floats2half2_rn(w.z, w.w);
    }
    float4 w2a = *reinterpret_cast<const float4*>(&Wm2[8 * li]);
    float4 w2b = *reinterpret_cast<const float4*>(&Wm2[8 * li + 4]);
    float4 bb = *reinterpret_cast<const float4*>(&bm1[4 * li]);
    float c0 = bm2[0], c1 = bm2[1];

    // hoist 64 edge indices (coalesced)
    int ecl = min(e0 + lane, E - 1);
    int sv = src[ecl], dv = dst[ecl];

    // hoist ea for 64 edges -> 8 packed half2 per lane
    int hzi[8];
    size_t eabase = (size_t)e0 * 16;
    size_t eamax = (size_t)E * 16 - 4;
#pragma unroll
    for (int j = 0; j < 4; j++) {
        size_t off = eabase + 256 * j + 4 * lane;
        float4 f = *reinterpret_cast<const float4*>(ea + min(off, eamax));
        __half2 a = __floats2half2_rn(f.x, f.y);
        __half2 b = __floats2half2_rn(f.z, f.w);
        hzi[2 * j] = *reinterpret_cast<int*>(&a);
        hzi[2 * j + 1] = *reinterpret_cast<int*>(&b);
    }

    uint2 rs[8], rd[8];
#define ISSUE(p, slot)                                                      \
    {                                                                       \
        int idx = 4 * (p) + g;                                              \
        int s = __shfl(sv, idx);                                            \
        int d = __shfl(dv, idx);                                            \
        rs[slot] = *reinterpret_cast<const uint2*>(&Ps[(size_t)s * 64 + 4 * li]); \
        rd[slot] = *reinterpret_cast<const uint2*>(&Pd[(size_t)d * 64 + 4 * li]); \
    }
    ISSUE(0, 0) ISSUE(1, 1) ISSUE(2, 2) ISSUE(3, 3)
    ISSUE(4, 4) ISSUE(5, 5) ISSUE(6, 6) ISSUE(7, 7)

#pragma unroll
    for (int p = 0; p < 16; p++) {
        const int slot = p & 7;
        uint2 crs = rs[slot], crd = rd[slot];
        if (p + 8 < 16) ISSUE(p + 8, slot)

        // q = ea[e] @ We (packed fp16)
        __half2 q0 = __floats2half2_rn(0.f, 0.f);
        __half2 q1 = q0;
#pragma unroll
        for (int m = 0; m < 8; m++) {
            int srcl = 16 * (p & 3) + 4 * g + (m >> 1);
            int u = __shfl(hzi[2 * (p >> 2) + (m & 1)], srcl);
            __half2 tt = *reinterpret_cast<__half2*>(&u);
            __half2 t0 = __low2half2(tt);
            __half2 t1 = __high2half2(tt);
            q0 = __hfma2(t0, wc[2 * m][0], q0);
            q1 = __hfma2(t0, wc[2 * m][1], q1);
            q0 = __hfma2(t1, wc[2 * m + 1][0], q0);
            q1 = __hfma2(t1, wc[2 * m + 1][1], q1);
        }
        float2 q0f = __half22float2(q0);
        float2 q1f = __half22float2(q1);

        float2 ps0 = __half22float2(*reinterpret_cast<__half2*>(&crs.x));
        float2 ps1 = __half22float2(*reinterpret_cast<__half2*>(&crs.y));
        float2 pd0 = __half22float2(*reinterpret_cast<__half2*>(&crd.x));
        float2 pd1 = __half22float2(*reinterpret_cast<__half2*>(&crd.y));

        float4 u4;
        u4.x = fmaxf(ps0.x + pd0.x + q0f.x + bb.x, 0.f);
        u4.y = fmaxf(ps0.y + pd0.y + q0f.y + bb.y, 0.f);
        u4.z = fmaxf(ps1.x + pd1.x + q1f.x + bb.z, 0.f);
        u4.w = fmaxf(ps1.y + pd1.y + q1f.y + bb.w, 0.f);
        float p0 = u4.x * w2a.x + u4.y * w2a.z + u4.z * w2b.x + u4.w * w2b.z;
        float p1 = u4.x * w2a.y + u4.y * w2a.w + u4.z * w2b.y + u4.w * w2b.w;
#pragma unroll
        for (int off = 1; off < 16; off <<= 1) {
            p0 += __shfl_xor(p0, off);
            p1 += __shfl_xor(p1, off);
        }
        int e = e0 + 4 * p + g;
        if (li == 0 && e < E) {
            float2 o = make_float2(p0 + c0, p1 + c1);
            *reinterpret_cast<float2*>(&out[(size_t)e * 2]) = o;
        }
    }
#undef ISSUE
}

static inline size_t align256(size_t x) { return (x + 255) & ~(size_t)255; }

extern "C" void kernel_launch(void* const* d_in, const int* in_sizes, int n_in,
                              void* d_out, int out_size, void* d_ws, size_t ws_size,
                              hipStream_t stream) {
    const float* x = (const float*)d_in[0];
    const int* ei = (const int*)d_in[1];
    const float* ea = (const float*)d_in[2];
    const float* W1 = (const float*)d_in[3];
    const float* b1 = (const float*)d_in[4];
    const float* W2 = (const float*)d_in[5];
    const float* b2 = (const float*)d_in[6];
    const float* Wm1 = (const float*)d_in[7];
    const float* bm1 = (const float*)d_in[8];
    const float* Wm2 = (const float*)d_in[9];
    const float* bm2 = (const float*)d_in[10];

    const int N = in_sizes[0] / 128;  // 50000
    const int E = in_sizes[1] / 2;    // 800000
    const int* src = ei;
    const int* dst = ei + E;
    float* out = (float*)d_out;

    const int NB = (N + 255) / 256;  // scan blocks (196)

    // ws layout (256B-aligned chunks)
    char* p = (char*)d_ws;
    int* cnt = (int*)p;        p += align256((size_t)N * 4);
    int* rank = (int*)p;       p += align256((size_t)E * 4);
    int* row_ptr = (int*)p;    p += align256((size_t)(N + 1) * 4);
    int* bsum = (int*)p;       p += align256((size_t)NB * 4);
    int* csr_src = (int*)p;    p += align256((size_t)E * 4);
    float* dinv = (float*)p;   p += align256((size_t)N * 4);
    __half* A16 = (__half*)p;  p += align256((size_t)N * 64 * 2);
    float* B = (float*)p;      p += align256((size_t)N * 64 * 4);
    __half* Ps16 = (__half*)p; p += align256((size_t)N * 64 * 2);
    __half* Pd16 = (__half*)p;

    // ---- CSR build (counting sort by dst; fill is atomic-free) ----
    hipMemsetAsync(cnt, 0, (size_t)N * sizeof(int), stream);
    k_count<<<(E + 255) / 256, 256, 0, stream>>>(dst, cnt, rank, E);
    k_bsum<<<NB, 256, 0, stream>>>(cnt, bsum, dinv, N);
    k_scanb<<<1, 256, 0, stream>>>(bsum, NB);
    k_scan3<<<NB, 256, 0, stream>>>(cnt, bsum, row_ptr, N, E);
    k_fill<<<(E + 255) / 256, 256, 0, stream>>>(src, dst, row_ptr, rank, csr_src, E);

    // ---- Layer 1 ----
    k_gemm<128, false, true, __half><<<(N + 63) / 64, 256, 0, stream>>>(
        x, W1, dinv, A16, N);
    k_agg<<<(N + 15) / 16, 256, 0, stream>>>(A16, row_ptr, csr_src, dinv, b1, B, N);

    // ---- Layer 2 ----
    k_gemm<64, true, true, __half><<<(N + 63) / 64, 256, 0, stream>>>(
        B, W2, dinv, A16, N);
    k_agg<<<(N + 15) / 16, 256, 0, stream>>>(A16, row_ptr, csr_src, dinv, b2, B, N);

    // ---- Edge MLP, decomposed ----
    k_proj<<<(N + 63) / 64, 256, 0, stream>>>(B, Wm1, Wm1 + 64 * 64, Ps16, Pd16, N);
    int waves = (E + 63) / 64;
    k_edge<<<(waves + 3) / 4, 256, 0, stream>>>(Ps16, Pd16, src, dst, ea,
                                                Wm1 + 128 * 64, bm1, Wm2, bm2,
                                                out, E);
}

// Round 7
// 351.749 us; speedup vs baseline: 18.0654x; 1.0024x over previous
//
#include <hip/hip_runtime.h>
#include <hip/hip_fp16.h>

// ---------------------------------------------------------------------------
// EdgeClassifierGNN: 2x GCNConv (128->64->64, sym-norm, self-loops) + edge MLP
// Round 7: R6's 8-deep k_edge pipeline SPILLED (VGPR pinned at 64 by bare
// __launch_bounds__(256)). Fix: __launch_bounds__(256,4) -> 128-VGPR budget.
// Same for k_agg + 8-deep gather pipeline there.
// ---------------------------------------------------------------------------

__device__ __forceinline__ void fma4(float4& a, float s, const float4& b) {
    a.x = fmaf(s, b.x, a.x);
    a.y = fmaf(s, b.y, a.y);
    a.z = fmaf(s, b.z, a.z);
    a.w = fmaf(s, b.w, a.w);
}

__device__ __forceinline__ float4 relu4(float4 v) {
    v.x = fmaxf(v.x, 0.f); v.y = fmaxf(v.y, 0.f);
    v.z = fmaxf(v.z, 0.f); v.w = fmaxf(v.w, 0.f);
    return v;
}

__device__ __forceinline__ void store4(float* C, size_t idx, float4 v) {
    *reinterpret_cast<float4*>(C + idx) = v;
}
__device__ __forceinline__ void store4(__half* C, size_t idx, float4 v) {
    __half2 lo = __floats2half2_rn(v.x, v.y);
    __half2 hi = __floats2half2_rn(v.z, v.w);
    uint2 raw;
    raw.x = *reinterpret_cast<unsigned*>(&lo);
    raw.y = *reinterpret_cast<unsigned*>(&hi);
    *reinterpret_cast<uint2*>(C + idx) = raw;
}

// cnt[d]++ per edge; rank[e] = arrival order of e within its dst bucket
__global__ void k_count(const int* __restrict__ dst, int* __restrict__ cnt,
                        int* __restrict__ rank, int E) {
    int e = blockIdx.x * 256 + threadIdx.x;
    if (e < E) rank[e] = atomicAdd(&cnt[dst[e]], 1);
}

// block sums for scan + dinv = rsqrt(cnt+1) (fused)
__global__ void k_bsum(const int* __restrict__ cnt, int* __restrict__ bsum,
                       float* __restrict__ dinv, int N) {
    int i = blockIdx.x * 256 + threadIdx.x;
    int v = (i < N) ? cnt[i] : 0;
    if (i < N) dinv[i] = rsqrtf((float)v + 1.0f);
    int r = v;
#pragma unroll
    for (int d = 1; d < 64; d <<= 1) r += __shfl_xor(r, d);
    __shared__ int ws[4];
    if ((threadIdx.x & 63) == 0) ws[threadIdx.x >> 6] = r;
    __syncthreads();
    if (threadIdx.x == 0) bsum[blockIdx.x] = ws[0] + ws[1] + ws[2] + ws[3];
}

// in-place exclusive scan of bsum[0..nb), nb <= 256, single block
__global__ void k_scanb(int* __restrict__ bsum, int nb) {
    int t = threadIdx.x;
    int lane = t & 63, w = t >> 6;
    int v = (t < nb) ? bsum[t] : 0;
    int x = v;
#pragma unroll
    for (int d = 1; d < 64; d <<= 1) {
        int y = __shfl_up(x, d);
        if (lane >= d) x += y;
    }
    __shared__ int ws[4];
    if (lane == 63) ws[w] = x;
    __syncthreads();
    int woff = 0;
    for (int j = 0; j < w; j++) woff += ws[j];
    if (t < nb) bsum[t] = woff + x - v;
}

// row_ptr[i] = bsum[blk] + exclusive_scan_within_block(cnt); row_ptr[N] = E
__global__ void k_scan3(const int* __restrict__ cnt, const int* __restrict__ bsum,
                        int* __restrict__ row_ptr, int N, int E) {
    int t = threadIdx.x, b = blockIdx.x;
    int i = b * 256 + t;
    int lane = t & 63, w = t >> 6;
    int v = (i < N) ? cnt[i] : 0;
    int x = v;
#pragma unroll
    for (int d = 1; d < 64; d <<= 1) {
        int y = __shfl_up(x, d);
        if (lane >= d) x += y;
    }
    __shared__ int ws[4];
    if (lane == 63) ws[w] = x;
    __syncthreads();
    int woff = 0;
    for (int j = 0; j < w; j++) woff += ws[j];
    if (i < N) row_ptr[i] = bsum[b] + woff + x - v;
    if (i == 0) row_ptr[N] = E;
}

// atomic-free: csr_src[row_ptr[dst[e]] + rank[e]] = src[e]
__global__ void k_fill(const int* __restrict__ src, const int* __restrict__ dst,
                       const int* __restrict__ row_ptr, const int* __restrict__ rank,
                       int* __restrict__ csr_src, int E) {
    int e = blockIdx.x * 256 + threadIdx.x;
    if (e >= E) return;
    csr_src[row_ptr[dst[e]] + rank[e]] = src[e];
}

// C[M x 64] = (SCALE? dinv[row] : 1) * (op(A[M x K]) @ B[K x 64]); op=relu if RELU_A
template<int K, bool RELU_A, bool SCALE, typename OutT>
__global__ __launch_bounds__(256) void k_gemm(const float* __restrict__ A,
                                              const float* __restrict__ B,
                                              const float* __restrict__ dinv,
                                              OutT* __restrict__ C, int M) {
    constexpr int AS = K + 4;
    __shared__ float As[64 * AS];
    __shared__ float Bs[64 * 64];
    const int t = threadIdx.x;
    const int r0 = blockIdx.x * 64;

    constexpr int C4 = K / 4;
    for (int idx = t; idx < 64 * C4; idx += 256) {
        int row = idx / C4, c4 = idx % C4;
        float4 v = make_float4(0.f, 0.f, 0.f, 0.f);
        if (r0 + row < M)
            v = reinterpret_cast<const float4*>(A + (size_t)(r0 + row) * K)[c4];
        if (RELU_A) v = relu4(v);
        *reinterpret_cast<float4*>(&As[row * AS + 4 * c4]) = v;
    }

    const int tx = t & 15, ty = t >> 4;
    float4 acc[4];
    acc[0] = acc[1] = acc[2] = acc[3] = make_float4(0.f, 0.f, 0.f, 0.f);

    for (int c = 0; c < K / 64; c++) {
        __syncthreads();
        for (int idx = t; idx < 64 * 16; idx += 256)
            reinterpret_cast<float4*>(Bs)[idx] =
                reinterpret_cast<const float4*>(B + (size_t)c * 64 * 64)[idx];
        __syncthreads();
#pragma unroll
        for (int k0 = 0; k0 < 64; k0 += 4) {
            float4 b0 = *reinterpret_cast<const float4*>(&Bs[(k0 + 0) * 64 + 4 * tx]);
            float4 b1 = *reinterpret_cast<const float4*>(&Bs[(k0 + 1) * 64 + 4 * tx]);
            float4 b2 = *reinterpret_cast<const float4*>(&Bs[(k0 + 2) * 64 + 4 * tx]);
            float4 b3 = *reinterpret_cast<const float4*>(&Bs[(k0 + 3) * 64 + 4 * tx]);
#pragma unroll
            for (int i = 0; i < 4; i++) {
                float4 a = *reinterpret_cast<const float4*>(
                    &As[(4 * ty + i) * AS + c * 64 + k0]);
                fma4(acc[i], a.x, b0);
                fma4(acc[i], a.y, b1);
                fma4(acc[i], a.z, b2);
                fma4(acc[i], a.w, b3);
            }
        }
    }

#pragma unroll
    for (int i = 0; i < 4; i++) {
        int row = r0 + 4 * ty + i;
        if (row < M) {
            float4 o = acc[i];
            if (SCALE) {
                float di = dinv[row];
                o = make_float4(di * o.x, di * o.y, di * o.z, di * o.w);
            }
            store4(C, (size_t)row * 64 + 4 * tx, o);
        }
    }
}

// Fused projections: C0 = relu(A)@B0, C1 = relu(A)@B1 (A staged once), fp16 out
__global__ __launch_bounds__(256) void k_proj(const float* __restrict__ A,
                                              const float* __restrict__ B0,
                                              const float* __restrict__ B1,
                                              __half* __restrict__ C0,
                                              __half* __restrict__ C1, int M) {
    constexpr int AS = 68;
    __shared__ float As[64 * AS];
    __shared__ float Bs[64 * 64];
    const int t = threadIdx.x;
    const int r0 = blockIdx.x * 64;

    for (int idx = t; idx < 64 * 16; idx += 256) {
        int row = idx / 16, c4 = idx % 16;
        float4 v = make_float4(0.f, 0.f, 0.f, 0.f);
        if (r0 + row < M)
            v = relu4(reinterpret_cast<const float4*>(A + (size_t)(r0 + row) * 64)[c4]);
        *reinterpret_cast<float4*>(&As[row * AS + 4 * c4]) = v;
    }

    const int tx = t & 15, ty = t >> 4;
    for (int m = 0; m < 2; m++) {
        const float* B = m ? B1 : B0;
        __half* C = m ? C1 : C0;
        __syncthreads();
        for (int idx = t; idx < 64 * 16; idx += 256)
            reinterpret_cast<float4*>(Bs)[idx] =
                reinterpret_cast<const float4*>(B)[idx];
        __syncthreads();
        float4 acc[4];
        acc[0] = acc[1] = acc[2] = acc[3] = make_float4(0.f, 0.f, 0.f, 0.f);
#pragma unroll
        for (int k0 = 0; k0 < 64; k0 += 4) {
            float4 b0 = *reinterpret_cast<const float4*>(&Bs[(k0 + 0) * 64 + 4 * tx]);
            float4 b1 = *reinterpret_cast<const float4*>(&Bs[(k0 + 1) * 64 + 4 * tx]);
            float4 b2 = *reinterpret_cast<const float4*>(&Bs[(k0 + 2) * 64 + 4 * tx]);
            float4 b3 = *reinterpret_cast<const float4*>(&Bs[(k0 + 3) * 64 + 4 * tx]);
#pragma unroll
            for (int i = 0; i < 4; i++) {
                float4 a = *reinterpret_cast<const float4*>(&As[(4 * ty + i) * AS + k0]);
                fma4(acc[i], a.x, b0);
                fma4(acc[i], a.y, b1);
                fma4(acc[i], a.z, b2);
                fma4(acc[i], a.w, b3);
            }
        }
#pragma unroll
        for (int i = 0; i < 4; i++) {
            int row = r0 + 4 * ty + i;
            if (row < M) store4(C, (size_t)row * 64 + 4 * tx, acc[i]);
        }
    }
}

// 4 nodes/wave, 16 lanes/node, uint2 (4 fp16)/lane, 8-deep gather pipeline:
// out[d] = bias + dinv[d]*(A16[d] + sum_s A16[s])
__global__ __launch_bounds__(256, 4) void k_agg(const __half* __restrict__ A16,
                                                const int* __restrict__ row_ptr,
                                                const int* __restrict__ csr_src,
                                                const float* __restrict__ dinv,
                                                const float* __restrict__ bias,
                                                float* __restrict__ out, int N) {
    int gw = (blockIdx.x * 256 + threadIdx.x) >> 6;  // global wave
    int sub = (threadIdx.x >> 4) & 3;
    int l = threadIdx.x & 15;
    int node = gw * 4 + sub;
    if (node >= N) return;
    const uint2* A4 = reinterpret_cast<const uint2*>(A16);  // row = 16 uint2

    int beg = row_ptr[node], end = row_ptr[node + 1];
    uint2 selfv = A4[(size_t)node * 16 + l];
    float2 a0 = __half22float2(*reinterpret_cast<__half2*>(&selfv.x));
    float2 a1 = __half22float2(*reinterpret_cast<__half2*>(&selfv.y));
    float4 acc = make_float4(a0.x, a0.y, a1.x, a1.y);

#define ACC(u)                                                          \
    {                                                                   \
        float2 f0 = __half22float2(*reinterpret_cast<__half2*>(&u.x));  \
        float2 f1 = __half22float2(*reinterpret_cast<__half2*>(&u.y));  \
        acc.x += f0.x; acc.y += f0.y; acc.z += f1.x; acc.w += f1.y;     \
    }
    for (int p = beg; p < end; p += 16) {
        int m = min(16, end - p);
        int sl = (p + l < end) ? csr_src[p + l] : 0;
        int j = 0;
        for (; j + 7 < m; j += 8) {
            uint2 u0 = A4[(size_t)__shfl(sl, j + 0, 16) * 16 + l];
            uint2 u1 = A4[(size_t)__shfl(sl, j + 1, 16) * 16 + l];
            uint2 u2 = A4[(size_t)__shfl(sl, j + 2, 16) * 16 + l];
            uint2 u3 = A4[(size_t)__shfl(sl, j + 3, 16) * 16 + l];
            uint2 u4 = A4[(size_t)__shfl(sl, j + 4, 16) * 16 + l];
            uint2 u5 = A4[(size_t)__shfl(sl, j + 5, 16) * 16 + l];
            uint2 u6 = A4[(size_t)__shfl(sl, j + 6, 16) * 16 + l];
            uint2 u7 = A4[(size_t)__shfl(sl, j + 7, 16) * 16 + l];
            ACC(u0) ACC(u1) ACC(u2) ACC(u3) ACC(u4) ACC(u5) ACC(u6) ACC(u7)
        }
        for (; j + 3 < m; j += 4) {
            uint2 u0 = A4[(size_t)__shfl(sl, j + 0, 16) * 16 + l];
            uint2 u1 = A4[(size_t)__shfl(sl, j + 1, 16) * 16 + l];
            uint2 u2 = A4[(size_t)__shfl(sl, j + 2, 16) * 16 + l];
            uint2 u3 = A4[(size_t)__shfl(sl, j + 3, 16) * 16 + l];
            ACC(u0) ACC(u1) ACC(u2) ACC(u3)
        }
        for (; j < m; j++) {
            uint2 u0 = A4[(size_t)__shfl(sl, j, 16) * 16 + l];
            ACC(u0)
        }
    }
#undef ACC
    float di = dinv[node];
    float4 bb = *reinterpret_cast<const float4*>(&bias[4 * l]);
    float4 o = make_float4(fmaf(di, acc.x, bb.x), fmaf(di, acc.y, bb.y),
                           fmaf(di, acc.z, bb.z), fmaf(di, acc.w, bb.w));
    *reinterpret_cast<float4*>(&out[(size_t)node * 64 + 4 * l]) = o;
}

// Edge epilogue: out[e] = relu(Ps[s] + Pd[d] + ea@We + bm1) @ Wm2 + bm2
// Per wave: 64 edges. Indices + ea hoisted, 8-deep gather pipeline (needs
// ~100 VGPRs -> launch_bounds(256,4) caps at 128, avoids R6's scratch spill).
__global__ __launch_bounds__(256, 4) void k_edge(
    const __half* __restrict__ Ps, const __half* __restrict__ Pd,
    const int* __restrict__ src, const int* __restrict__ dst,
    const float* __restrict__ ea, const float* __restrict__ We,
    const float* __restrict__ bm1, const float* __restrict__ Wm2,
    const float* __restrict__ bm2, float* __restrict__ out, int E) {
    const int lane = threadIdx.x & 63;
    const int wid = (blockIdx.x * 256 + threadIdx.x) >> 6;
    const int li = lane & 15, g = lane >> 4;
    const int e0 = wid * 64;
    if (e0 >= E) return;

    __half2 wc[16][2];
#pragma unroll
    for (int k = 0; k < 16; k++) {
        float4 w = *reinterpret_cast<const float4*>(&We[k * 64 + 4 * li]);
        wc[k][0] = __floats2half2_rn(w.x, w.y);
        wc[k][1] = __floats2half2_rn(w.z, w.w);
    }
    float4 w2a = *reinterpret_cast<const float4*>(&Wm2[8 * li]);
    float4 w2b = *reinterpret_cast<const float4*>(&Wm2[8 * li + 4]);
    float4 bb = *reinterpret_cast<const float4*>(&bm1[4 * li]);
    float c0 = bm2[0], c1 = bm2[1];

    // hoist 64 edge indices (coalesced)
    int ecl = min(e0 + lane, E - 1);
    int sv = src[ecl], dv = dst[ecl];

    // hoist ea for 64 edges -> 8 packed half2 per lane
    int hzi[8];
    size_t eabase = (size_t)e0 * 16;
    size_t eamax = (size_t)E * 16 - 4;
#pragma unroll
    for (int j = 0; j < 4; j++) {
        size_t off = eabase + 256 * j + 4 * lane;
        float4 f = *reinterpret_cast<const float4*>(ea + min(off, eamax));
        __half2 a = __floats2half2_rn(f.x, f.y);
        __half2 b = __floats2half2_rn(f.z, f.w);
        hzi[2 * j] = *reinterpret_cast<int*>(&a);
        hzi[2 * j + 1] = *reinterpret_cast<int*>(&b);
    }

    uint2 rs[8], rd[8];
#define ISSUE(p, slot)                                                      \
    {                                                                       \
        int idx = 4 * (p) + g;                                              \
        int s = __shfl(sv, idx);                                            \
        int d = __shfl(dv, idx);                                            \
        rs[slot] = *reinterpret_cast<const uint2*>(&Ps[(size_t)s * 64 + 4 * li]); \
        rd[slot] = *reinterpret_cast<const uint2*>(&Pd[(size_t)d * 64 + 4 * li]); \
    }
    ISSUE(0, 0) ISSUE(1, 1) ISSUE(2, 2) ISSUE(3, 3)
    ISSUE(4, 4) ISSUE(5, 5) ISSUE(6, 6) ISSUE(7, 7)

#pragma unroll
    for (int p = 0; p < 16; p++) {
        const int slot = p & 7;
        uint2 crs = rs[slot], crd = rd[slot];
        if (p + 8 < 16) ISSUE(p + 8, slot)

        // q = ea[e] @ We (packed fp16)
        __half2 q0 = __floats2half2_rn(0.f, 0.f);
        __half2 q1 = q0;
#pragma unroll
        for (int m = 0; m < 8; m++) {
            int srcl = 16 * (p & 3) + 4 * g + (m >> 1);
            int u = __shfl(hzi[2 * (p >> 2) + (m & 1)], srcl);
            __half2 tt = *reinterpret_cast<__half2*>(&u);
            __half2 t0 = __low2half2(tt);
            __half2 t1 = __high2half2(tt);
            q0 = __hfma2(t0, wc[2 * m][0], q0);
            q1 = __hfma2(t0, wc[2 * m][1], q1);
            q0 = __hfma2(t1, wc[2 * m + 1][0], q0);
            q1 = __hfma2(t1, wc[2 * m + 1][1], q1);
        }
        float2 q0f = __half22float2(q0);
        float2 q1f = __half22float2(q1);

        float2 ps0 = __half22float2(*reinterpret_cast<__half2*>(&crs.x));
        float2 ps1 = __half22float2(*reinterpret_cast<__half2*>(&crs.y));
        float2 pd0 = __half22float2(*reinterpret_cast<__half2*>(&crd.x));
        float2 pd1 = __half22float2(*reinterpret_cast<__half2*>(&crd.y));

        float4 u4;
        u4.x = fmaxf(ps0.x + pd0.x + q0f.x + bb.x, 0.f);
        u4.y = fmaxf(ps0.y + pd0.y + q0f.y + bb.y, 0.f);
        u4.z = fmaxf(ps1.x + pd1.x + q1f.x + bb.z, 0.f);
        u4.w = fmaxf(ps1.y + pd1.y + q1f.y + bb.w, 0.f);
        float p0 = u4.x * w2a.x + u4.y * w2a.z + u4.z * w2b.x + u4.w * w2b.z;
        float p1 = u4.x * w2a.y + u4.y * w2a.w + u4.z * w2b.y + u4.w * w2b.w;
#pragma unroll
        for (int off = 1; off < 16; off <<= 1) {
            p0 += __shfl_xor(p0, off);
            p1 += __shfl_xor(p1, off);
        }
        int e = e0 + 4 * p + g;
        if (li == 0 && e < E) {
            float2 o = make_float2(p0 + c0, p1 + c1);
            *reinterpret_cast<float2*>(&out[(size_t)e * 2]) = o;
        }
    }
#undef ISSUE
}

static inline size_t align256(size_t x) { return (x + 255) & ~(size_t)255; }

extern "C" void kernel_launch(void* const* d_in, const int* in_sizes, int n_in,
                              void* d_out, int out_size, void* d_ws, size_t ws_size,
                              hipStream_t stream) {
    const float* x = (const float*)d_in[0];
    const int* ei = (const int*)d_in[1];
    const float* ea = (const float*)d_in[2];
    const float* W1 = (const float*)d_in[3];
    const float* b1 = (const float*)d_in[4];
    const float* W2 = (const float*)d_in[5];
    const float* b2 = (const float*)d_in[6];
    const float* Wm1 = (const float*)d_in[7];
    const float* bm1 = (const float*)d_in[8];
    const float* Wm2 = (const float*)d_in[9];
    const float* bm2 = (const float*)d_in[10];

    const int N = in_sizes[0] / 128;  // 50000
    const int E = in_sizes[1] / 2;    // 800000
    const int* src = ei;
    const int* dst = ei + E;
    float* out = (float*)d_out;

    const int NB = (N + 255) / 256;  // scan blocks (196)

    // ws layout (256B-aligned chunks)
    char* p = (char*)d_ws;
    int* cnt = (int*)p;        p += align256((size_t)N * 4);
    int* rank = (int*)p;       p += align256((size_t)E * 4);
    int* row_ptr = (int*)p;    p += align256((size_t)(N + 1) * 4);
    int* bsum = (int*)p;       p += align256((size_t)NB * 4);
    int* csr_src = (int*)p;    p += align256((size_t)E * 4);
    float* dinv = (float*)p;   p += align256((size_t)N * 4);
    __half* A16 = (__half*)p;  p += align256((size_t)N * 64 * 2);
    float* B = (float*)p;      p += align256((size_t)N * 64 * 4);
    __half* Ps16 = (__half*)p; p += align256((size_t)N * 64 * 2);
    __half* Pd16 = (__half*)p;

    // ---- CSR build (counting sort by dst; fill is atomic-free) ----
    hipMemsetAsync(cnt, 0, (size_t)N * sizeof(int), stream);
    k_count<<<(E + 255) / 256, 256, 0, stream>>>(dst, cnt, rank, E);
    k_bsum<<<NB, 256, 0, stream>>>(cnt, bsum, dinv, N);
    k_scanb<<<1, 256, 0, stream>>>(bsum, NB);
    k_scan3<<<NB, 256, 0, stream>>>(cnt, bsum, row_ptr, N, E);
    k_fill<<<(E + 255) / 256, 256, 0, stream>>>(src, dst, row_ptr, rank, csr_src, E);

    // ---- Layer 1 ----
    k_gemm<128, false, true, __half><<<(N + 63) / 64, 256, 0, stream>>>(
        x, W1, dinv, A16, N);
    k_agg<<<(N + 15) / 16, 256, 0, stream>>>(A16, row_ptr, csr_src, dinv, b1, B, N);

    // ---- Layer 2 ----
    k_gemm<64, true, true, __half><<<(N + 63) / 64, 256, 0, stream>>>(
        B, W2, dinv, A16, N);
    k_agg<<<(N + 15) / 16, 256, 0, stream>>>(A16, row_ptr, csr_src, dinv, b2, B, N);

    // ---- Edge MLP, decomposed ----
    k_proj<<<(N + 63) / 64, 256, 0, stream>>>(B, Wm1, Wm1 + 64 * 64, Ps16, Pd16, N);
    int waves = (E + 63) / 64;
    k_edge<<<(waves + 3) / 4, 256, 0, stream>>>(Ps16, Pd16, src, dst, ea,
                                                Wm1 + 128 * 64, bm1, Wm2, bm2,
                                                out, E);
}